// Round 6
// baseline (2446.058 us; speedup 1.0000x reference)
//
#include <hip/hip_runtime.h>

typedef __bf16 bf16;
typedef __bf16 bf16x4 __attribute__((ext_vector_type(4)));
typedef __bf16 bf16x8 __attribute__((ext_vector_type(8)));
typedef float  f32x4  __attribute__((ext_vector_type(4)));

static constexpr int kC   = 1024;
static constexpr int kT   = 1024;
static constexpr int kB   = 4;
static constexpr int kH   = 16;
static constexpr int kHD  = 64;
static constexpr int kL   = 4;
static constexpr int kFF  = 100;
static constexpr int kFFP = 128;
static constexpr int kM   = kB * kT;

// async global->LDS, 16B per lane; LDS dest must be wave-uniform (HW adds lane*16)
__device__ __forceinline__ void gload16(const bf16* g, bf16* l)
{
    __builtin_amdgcn_global_load_lds(
        (const __attribute__((address_space(1))) void*)g,
        (__attribute__((address_space(3))) void*)l, 16, 0, 0);
}

// ---------------------------------------------------------------------------
__global__ __launch_bounds__(256)
void trans_cvt(const float* __restrict__ src, long sStride,
               bf16* __restrict__ dst, long dStride,
               int K, int N, int KP, int NP)
{
    __shared__ float tile[32][33];
    const int z = blockIdx.z;
    src += (long)z * sStride;
    dst += (long)z * dStride;
    const int n0 = blockIdx.x * 32, k0 = blockIdx.y * 32;
    const int tx = threadIdx.x & 31, ty = threadIdx.x >> 5;
#pragma unroll
    for (int i = 0; i < 4; ++i) {
        int k = k0 + ty + i * 8, n = n0 + tx;
        tile[ty + i * 8][tx] = (k < K && n < N) ? src[(long)k * N + n] : 0.f;
    }
    __syncthreads();
#pragma unroll
    for (int i = 0; i < 4; ++i) {
        int n = n0 + ty + i * 8, k = k0 + tx;
        if (n < NP && k < KP) dst[(long)n * KP + k] = (bf16)tile[tx][ty + i * 8];
    }
}

__global__ __launch_bounds__(256)
void pack_bias(const float* __restrict__ bq, const float* __restrict__ bk,
               const float* __restrict__ bv, float* __restrict__ dst)
{
    int gid = blockIdx.x * 256 + threadIdx.x;
    int l = gid / (3 * kC), w = (gid / kC) % 3, c = gid & (kC - 1);
    const float* s = (w == 0) ? bq : (w == 1) ? bk : bv;
    dst[gid] = s[l * kC + c];
}

__global__ __launch_bounds__(256)
void zero_kernel(float* __restrict__ p, int n)
{
    int i = blockIdx.x * 256 + threadIdx.x;
    if (i < n) p[i] = 0.f;
}

__global__ __launch_bounds__(256)
void embed_kernel(const int* __restrict__ idx, const float* __restrict__ tok,
                  const float* __restrict__ pos, float* __restrict__ x)
{
    const int m = blockIdx.x;
    const int c = threadIdx.x * 4;
    const int t = m & (kT - 1);
    const long tk = (long)idx[m] * kC;
    float4 a = *(const float4*)&tok[tk + c];
    float4 b = *(const float4*)&pos[(long)t * kC + c];
    float4 o; o.x = a.x + b.x; o.y = a.y + b.y; o.z = a.z + b.z; o.w = a.w + b.w;
    *(float4*)&x[(long)m * kC + c] = o;
}

__global__ __launch_bounds__(256)
void ln_kernel(const float* __restrict__ x, const float* __restrict__ g,
               const float* __restrict__ be, bf16* __restrict__ ob,
               float* __restrict__ of, int outf32)
{
    __shared__ float red[8];
    const long row = blockIdx.x;
    const int tid = threadIdx.x, lane = tid & 63, wv = tid >> 6;
    const float4 v = *(const float4*)&x[row * kC + tid * 4];
    float s = v.x + v.y + v.z + v.w;
    float s2 = v.x * v.x + v.y * v.y + v.z * v.z + v.w * v.w;
#pragma unroll
    for (int o = 32; o > 0; o >>= 1) { s += __shfl_down(s, o); s2 += __shfl_down(s2, o); }
    if (!lane) { red[wv] = s; red[4 + wv] = s2; }
    __syncthreads();
    s  = red[0] + red[1] + red[2] + red[3];
    s2 = red[4] + red[5] + red[6] + red[7];
    const float mean = s * (1.f / kC);
    const float var  = s2 * (1.f / kC) - mean * mean;
    const float rstd = rsqrtf(var + 1e-5f);
    const float4 gg = *(const float4*)&g[tid * 4];
    const float4 bb = *(const float4*)&be[tid * 4];
    float o0 = (v.x - mean) * rstd * gg.x + bb.x;
    float o1 = (v.y - mean) * rstd * gg.y + bb.y;
    float o2 = (v.z - mean) * rstd * gg.z + bb.z;
    float o3 = (v.w - mean) * rstd * gg.w + bb.w;
    if (outf32) {
        float4 o; o.x = o0; o.y = o1; o.z = o2; o.w = o3;
        *(float4*)&of[row * kC + tid * 4] = o;
    } else {
        bf16x4 o; o[0] = (bf16)o0; o[1] = (bf16)o1; o[2] = (bf16)o2; o[3] = (bf16)o3;
        *(bf16x4*)&ob[row * kC + tid * 4] = o;
    }
}

// ---------------------------------------------------------------------------
// MFMA GEMM: C[M,N] = A[M,K] * B^T[N,K]. GL=1: global_load_lds staging with
// 16B-block XOR swizzle (128x128 tile only). GL=0: reg-staged, padded LDS.
// MODE 0: QKV (z=0 q*0.125, z=1 k -> [B,H,T,HD]; z=2 v -> VT [B,H,HD,T])
// MODE 3: out bf16 = relu(acc + bias[gcol<kFF])
// MODE 4: resid[grow*N+gcol] += acc + bias[gcol]
// ---------------------------------------------------------------------------
template<int WAVES_M, int WAVES_N, int AI, int BJ, int MODE, int GL>
__global__ __launch_bounds__(256)
void gemm_bf16(const bf16* __restrict__ Ag, long strideA,
               const bf16* __restrict__ Bg, long strideB,
               const float* __restrict__ bias, int strideBias,
               bf16* __restrict__ outb, long strideOut,
               float* __restrict__ resid,
               int N, int K, int lda, int ldb)
{
    constexpr int BM = WAVES_M * AI * 16;
    constexpr int BN = WAVES_N * BJ * 16;
    constexpr int BK = 64;
    constexpr int LK = GL ? BK : (BK + 8);
    __shared__ __align__(16) bf16 As[BM * LK];
    __shared__ __align__(16) bf16 Bs[BN * LK];
    const int tid = threadIdx.x, lane = tid & 63, wv = tid >> 6;
    const int wm = wv / WAVES_N, wn = wv % WAVES_N;
    const int lr = lane & 15, lg = lane >> 4;
    const int z = blockIdx.z;
    const bf16* A = Ag + (long)z * strideA;
    const bf16* B = Bg + (long)z * strideB;
    const float* bi = bias ? bias + (long)z * strideBias : nullptr;
    const int m0 = blockIdx.y * BM, n0 = blockIdx.x * BN;

    f32x4 acc[AI][BJ];
#pragma unroll
    for (int i = 0; i < AI; ++i)
#pragma unroll
        for (int j = 0; j < BJ; ++j) acc[i][j] = (f32x4){0.f, 0.f, 0.f, 0.f};

    for (int k0 = 0; k0 < K; k0 += BK) {
        if constexpr (GL) {
            static_assert(BM == 128 && BN == 128, "GL path needs 128x128 tile");
            const int srow = wv * 32 + (lane >> 3);
            const int gcb  = (lane & 7) ^ (lane >> 3);
#pragma unroll
            for (int p = 0; p < 4; ++p) {
                gload16(A + (long)(m0 + srow + p * 8) * lda + k0 + gcb * 8,
                        &As[(wv * 32 + p * 8) * BK]);
                gload16(B + (long)(n0 + srow + p * 8) * ldb + k0 + gcb * 8,
                        &Bs[(wv * 32 + p * 8) * BK]);
            }
        } else {
            constexpr int AP = (BM * BK) / (256 * 8);
#pragma unroll
            for (int p = 0; p < AP; ++p) {
                int r = p * 32 + (tid >> 3), c = (tid & 7) * 8;
                *(uint4*)&As[r * LK + c] = *(const uint4*)&A[(long)(m0 + r) * lda + k0 + c];
            }
            constexpr int BP = (BN * BK) / (256 * 8);
#pragma unroll
            for (int p = 0; p < BP; ++p) {
                int r = p * 32 + (tid >> 3), c = (tid & 7) * 8;
                *(uint4*)&Bs[r * LK + c] = *(const uint4*)&B[(long)(n0 + r) * ldb + k0 + c];
            }
        }
        __syncthreads();
#pragma unroll
        for (int kk = 0; kk < 2; ++kk) {
            bf16x8 af[AI], bfv[BJ];
#pragma unroll
            for (int i = 0; i < AI; ++i) {
                const int r = wm * AI * 16 + i * 16 + lr;
                const int c = GL ? (((kk * 4 + lg) ^ (lr & 7)) * 8) : (kk * 32 + lg * 8);
                af[i] = *(const bf16x8*)&As[r * LK + c];
            }
#pragma unroll
            for (int j = 0; j < BJ; ++j) {
                const int r = wn * BJ * 16 + j * 16 + lr;
                const int c = GL ? (((kk * 4 + lg) ^ (lr & 7)) * 8) : (kk * 32 + lg * 8);
                bfv[j] = *(const bf16x8*)&Bs[r * LK + c];
            }
#pragma unroll
            for (int i = 0; i < AI; ++i)
#pragma unroll
                for (int j = 0; j < BJ; ++j)
                    acc[i][j] = __builtin_amdgcn_mfma_f32_16x16x32_bf16(af[i], bfv[j], acc[i][j], 0, 0, 0);
        }
        __syncthreads();
    }

#pragma unroll
    for (int i = 0; i < AI; ++i)
#pragma unroll
        for (int j = 0; j < BJ; ++j)
#pragma unroll
            for (int rr = 0; rr < 4; ++rr) {
                const int grow = m0 + wm * AI * 16 + i * 16 + lg * 4 + rr;
                const int gcol = n0 + wn * BJ * 16 + j * 16 + lr;
                float v = acc[i][j][rr];
                if constexpr (MODE == 0) {
                    v += bi[gcol];
                    if (z == 0) v *= 0.125f;   // fold attention scale into Q
                    const int b = grow >> 10, t = grow & (kT - 1);
                    const int hh = gcol >> 6, hd = gcol & 63;
                    long o = (long)z * strideOut;
                    if (z == 2) o += (((long)b * kH + hh) * kHD + hd) * kT + t;  // VT
                    else        o += (((long)b * kH + hh) * kT + t) * kHD + hd;  // Q/K
                    outb[o] = (bf16)v;
                } else if constexpr (MODE == 3) {
                    v += (gcol < kFF) ? bi[gcol] : 0.f;
                    outb[(long)grow * N + gcol] = (bf16)fmaxf(v, 0.f);
                } else {
                    v += bi[gcol];
                    resid[(long)grow * N + gcol] += v;
                }
            }
}

// ---------------------------------------------------------------------------
// Fused attention v5: direct-L2 Q/K/V reads (XCD decode keeps them resident),
// no max-subtraction (|scores| < ~3 by construction, Q pre-scaled by 0.125),
// unnormalized E=exp(s) in half-width LDS (two PV k-passes), inv folded into
// the y epilogue. LDS = 33 KB -> 2 blocks/CU. 4 barriers per b.
// Block = (32 q-rows, h), loop b=0..3. Grid 512, 8 waves.
// ---------------------------------------------------------------------------
__global__ __launch_bounds__(512, 4)
void attn_fused(const bf16* __restrict__ Qg, const bf16* __restrict__ Kg,
                const bf16* __restrict__ VTg, bf16* __restrict__ yg,
                float* __restrict__ attm)
{
    __shared__ __align__(16) bf16 Ps[32 * 512];   // 32 KB: E half-tile (swizzled)
    __shared__ float reds[32][8];
    const int tid = threadIdx.x, lane = tid & 63, w = tid >> 6;
    const int lr = lane & 15, lg = lane >> 4;
    // XCD-aware decode: bid%8 = XCD (round-robin); h = 2*xcd + parity
    const int bid = blockIdx.x, r_ = bid >> 3;
    const int h = ((bid & 7) << 1) | (r_ & 1);
    const int q0 = (r_ >> 1) * 32;
    const int rh = w >> 2, ch = w & 3;            // PV: wave = one 16x16 y tile
    const int half = w >> 2;                      // which E-half this wave writes (w<4 -> 0)

    f32x4 am[2][8];                               // attm accumulator across b
#pragma unroll
    for (int i = 0; i < 2; ++i)
#pragma unroll
        for (int j = 0; j < 8; ++j) am[i][j] = (f32x4){0.f, 0.f, 0.f, 0.f};

    for (int b = 0; b < kB; ++b) {
        const long bh = (long)b * kH + h;
        const bf16* Qb = Qg + (bh * kT + q0) * kHD;
        const bf16* Kb = Kg + bh * kT * kHD;
        const bf16* Vb = VTg + bh * (long)kHD * kT;

        if (b) __syncthreads();   // prior-b PV pass-1 reads done before E rewrite

        // Q fragments direct from global (4 KB, L2-hot)
        bf16x8 af[2][2];
#pragma unroll
        for (int i = 0; i < 2; ++i)
#pragma unroll
            for (int kk = 0; kk < 2; ++kk)
                af[i][kk] = *(const bf16x8*)&Qb[(long)(i * 16 + lr) * kHD + kk * 32 + lg * 8];

        // QK^T: wave w owns cols w*128..+127; K fragments direct from L2
        f32x4 acc[2][8];
#pragma unroll
        for (int i = 0; i < 2; ++i)
#pragma unroll
            for (int j = 0; j < 8; ++j) acc[i][j] = (f32x4){0.f, 0.f, 0.f, 0.f};
#pragma unroll
        for (int jc = 0; jc < 8; jc += 4) {
            bf16x8 kf[4][2];
#pragma unroll
            for (int j4 = 0; j4 < 4; ++j4)
#pragma unroll
                for (int kk = 0; kk < 2; ++kk)
                    kf[j4][kk] = *(const bf16x8*)&Kb[(long)(w * 128 + (jc + j4) * 16 + lr) * kHD + kk * 32 + lg * 8];
#pragma unroll
            for (int j4 = 0; j4 < 4; ++j4)
#pragma unroll
                for (int kk = 0; kk < 2; ++kk) {
                    acc[0][jc + j4] = __builtin_amdgcn_mfma_f32_16x16x32_bf16(af[0][kk], kf[j4][kk], acc[0][jc + j4], 0, 0, 0);
                    acc[1][jc + j4] = __builtin_amdgcn_mfma_f32_16x16x32_bf16(af[1][kk], kf[j4][kk], acc[1][jc + j4], 0, 0, 0);
                }
        }

        // E = exp(s) (no max-sub; |s| bounded ~3) + row sum + half-0 E write
#pragma unroll
        for (int i = 0; i < 2; ++i)
#pragma unroll
            for (int rr = 0; rr < 4; ++rr) {
                float s = 0.f;
#pragma unroll
                for (int j = 0; j < 8; ++j) {
                    float e = __expf(acc[i][j][rr]);
                    acc[i][j][rr] = e;
                    s += e;
                }
#pragma unroll
                for (int off = 1; off < 16; off <<= 1) s += __shfl_xor(s, off);
                if (lr == 0) reds[i * 16 + lg * 4 + rr][w] = s;
            }
        if (half == 0) {   // waves 0-3 own cols 0..511 -> E half-0 into Ps
#pragma unroll
            for (int i = 0; i < 2; ++i)
#pragma unroll
                for (int rr = 0; rr < 4; ++rr) {
                    const int row = i * 16 + lg * 4 + rr;
#pragma unroll
                    for (int j = 0; j < 8; ++j) {
                        const int col = w * 128 + j * 16 + lr;   // < 512
                        Ps[row * 512 + (((col >> 3) ^ (row & 7)) << 3) + (col & 7)] = (bf16)acc[i][j][rr];
                    }
                }
        }
        __syncthreads();   // (1) reds + E half-0 visible

        float inv[2][4];
#pragma unroll
        for (int i = 0; i < 2; ++i)
#pragma unroll
            for (int rr = 0; rr < 4; ++rr) {
                const int row = i * 16 + lg * 4 + rr;
                float4 a = *(const float4*)&reds[row][0];
                float4 c = *(const float4*)&reds[row][4];
                inv[i][rr] = 1.f / ((a.x + a.y + a.z + a.w) + (c.x + c.y + c.z + c.w));
            }
        // attm accumulate: am += E * (inv/4)
#pragma unroll
        for (int i = 0; i < 2; ++i)
#pragma unroll
            for (int rr = 0; rr < 4; ++rr) {
                const float iv4 = inv[i][rr] * 0.25f;
#pragma unroll
                for (int j = 0; j < 8; ++j)
                    am[i][j][rr] += acc[i][j][rr] * iv4;
            }

        // PV pass 0 (t = 0..511)
        f32x4 yacc = (f32x4){0.f, 0.f, 0.f, 0.f};
        const int rowA = rh * 16 + lr;
        const long dRow = (long)(ch * 16 + lr) * kT;
#pragma unroll 4
        for (int kb = 0; kb < 16; ++kb) {
            const bf16x8 a = *(const bf16x8*)&Ps[rowA * 512 + (((kb * 4 + lg) ^ (rowA & 7)) << 3)];
            const bf16x8 v = *(const bf16x8*)&Vb[dRow + kb * 32 + lg * 8];
            yacc = __builtin_amdgcn_mfma_f32_16x16x32_bf16(a, v, yacc, 0, 0, 0);
        }
        __syncthreads();   // (2) pass-0 Ps reads done

        if (half == 1) {   // waves 4-7 own cols 512..1023 -> E half-1 into Ps
#pragma unroll
            for (int i = 0; i < 2; ++i)
#pragma unroll
                for (int rr = 0; rr < 4; ++rr) {
                    const int row = i * 16 + lg * 4 + rr;
#pragma unroll
                    for (int j = 0; j < 8; ++j) {
                        const int col = (w - 4) * 128 + j * 16 + lr;   // local 0..511
                        Ps[row * 512 + (((col >> 3) ^ (row & 7)) << 3) + (col & 7)] = (bf16)acc[i][j][rr];
                    }
                }
        }
        __syncthreads();   // (3) E half-1 visible

        // PV pass 1 (t = 512..1023)
#pragma unroll 4
        for (int kb = 0; kb < 16; ++kb) {
            const bf16x8 a = *(const bf16x8*)&Ps[rowA * 512 + (((kb * 4 + lg) ^ (rowA & 7)) << 3)];
            const bf16x8 v = *(const bf16x8*)&Vb[dRow + 512 + kb * 32 + lg * 8];
            yacc = __builtin_amdgcn_mfma_f32_16x16x32_bf16(a, v, yacc, 0, 0, 0);
        }
        // y = inv * (E·V)  (row scale; D-layout row = lg*4+rr of wave-half rh)
#pragma unroll
        for (int rr = 0; rr < 4; ++rr)
            yg[((long)b * kT + q0 + rh * 16 + lg * 4 + rr) * kC + h * kHD + ch * 16 + lr]
                = (bf16)(yacc[rr] * inv[rh][rr]);
    }

    __syncthreads();   // all PV reads done before fp32 reuse of Ps
    // attm write, coalesced via LDS: 4 quarters of [32][256] fp32 (32 KB)
    float* amf = (float*)Ps;
#pragma unroll
    for (int qd = 0; qd < 4; ++qd) {
        if ((w >> 1) == qd) {   // 2 waves own cols qd*256..+255
#pragma unroll
            for (int i = 0; i < 2; ++i)
#pragma unroll
                for (int rr = 0; rr < 4; ++rr) {
                    const int row = i * 16 + lg * 4 + rr;
#pragma unroll
                    for (int j = 0; j < 8; ++j)
                        amf[row * 256 + (w & 1) * 128 + j * 16 + lr] = am[i][j][rr];
                }
        }
        __syncthreads();
#pragma unroll
        for (int p = 0; p < 4; ++p) {
            const int f = p * 512 + tid;            // 2048 float4s
            const int row = f >> 6, c4 = f & 63;
            float4 v = *(const float4*)&amf[row * 256 + c4 * 4];
            *(float4*)&attm[((long)h * kT + q0 + row) * kT + qd * 256 + c4 * 4] = v;
        }
        __syncthreads();
    }
}

__global__ __launch_bounds__(256)
void pool_kernel(const float* __restrict__ xf, float* __restrict__ pooled)
{
    const int c = blockIdx.x * 256 + threadIdx.x;
    const int b = blockIdx.y;
    const int t0 = blockIdx.z * 128;
    float s = 0.f;
    for (int t = t0; t < t0 + 128; ++t) s += xf[((long)b * kT + t) * kC + c];
    atomicAdd(&pooled[b * kC + c], s * (1.f / kT));
}

// ---------------------------------------------------------------------------
extern "C" void kernel_launch(void* const* d_in, const int* in_sizes, int n_in,
                              void* d_out, int out_size, void* d_ws, size_t ws_size,
                              hipStream_t stream)
{
    const int*   idx  = (const int*)d_in[0];
    const float* tok  = (const float*)d_in[1];
    const float* pos  = (const float*)d_in[2];
    const float* Wq   = (const float*)d_in[3];
    const float* bq   = (const float*)d_in[4];
    const float* Wk   = (const float*)d_in[5];
    const float* bk   = (const float*)d_in[6];
    const float* Wv   = (const float*)d_in[7];
    const float* bv   = (const float*)d_in[8];
    const float* Wo   = (const float*)d_in[9];
    const float* bo   = (const float*)d_in[10];
    const float* ln1w = (const float*)d_in[11];
    const float* ln1b = (const float*)d_in[12];
    const float* ln2w = (const float*)d_in[13];
    const float* ln2b = (const float*)d_in[14];
    const float* W1   = (const float*)d_in[15];
    const float* b1   = (const float*)d_in[16];
    const float* W2   = (const float*)d_in[17];
    const float* b2   = (const float*)d_in[18];
    const float* lnfw = (const float*)d_in[19];
    const float* lnfb = (const float*)d_in[20];

    char* ws = (char*)d_ws;
    long off = 0;
    auto alloc = [&](long bytes) { char* p = ws + off; off += (bytes + 255) & ~255L; return p; };
    bf16*  WQKVT = (bf16*)alloc((long)kL * 3 * kC * kC * 2);
    bf16*  WOT   = (bf16*)alloc((long)kL * kC * kC * 2);
    bf16*  W1T   = (bf16*)alloc((long)kL * kFFP * kC * 2);
    bf16*  W2T   = (bf16*)alloc((long)kL * kC * kFFP * 2);
    float* BQKV  = (float*)alloc((long)kL * 3 * kC * 4);
    float* X     = (float*)alloc((long)kM * kC * 4);
    bf16*  Hbuf  = (bf16*)alloc((long)kM * kC * 2);
    bf16*  QKV   = (bf16*)alloc(3L * kM * kC * 2);
    bf16*  Y     = (bf16*)alloc((long)kM * kC * 2);
    bf16*  F1    = (bf16*)alloc((long)kM * kFFP * 2);
    float* XF    = (float*)alloc((long)kM * kC * 4);

    float* pooled = (float*)d_out;
    float* attm_base = pooled + kB * kC;

    zero_kernel<<<16, 256, 0, stream>>>(pooled, kB * kC);
    dim3 tg(32, 32, kL);
    trans_cvt<<<tg, 256, 0, stream>>>(Wq, (long)kC * kC, WQKVT + 0L * kC * kC, 3L * kC * kC, kC, kC, kC, kC);
    trans_cvt<<<tg, 256, 0, stream>>>(Wk, (long)kC * kC, WQKVT + 1L * kC * kC, 3L * kC * kC, kC, kC, kC, kC);
    trans_cvt<<<tg, 256, 0, stream>>>(Wv, (long)kC * kC, WQKVT + 2L * kC * kC, 3L * kC * kC, kC, kC, kC, kC);
    trans_cvt<<<tg, 256, 0, stream>>>(Wo, (long)kC * kC, WOT, (long)kC * kC, kC, kC, kC, kC);
    trans_cvt<<<dim3(4, 32, kL), 256, 0, stream>>>(W1, (long)kC * kFF, W1T, (long)kFFP * kC, kC, kFF, kC, kFFP);
    trans_cvt<<<dim3(32, 4, kL), 256, 0, stream>>>(W2, (long)kFF * kC, W2T, (long)kC * kFFP, kFF, kC, kFFP, kC);
    pack_bias<<<48, 256, 0, stream>>>(bq, bk, bv, BQKV);

    embed_kernel<<<kM, 256, 0, stream>>>(idx, tok, pos, X);

    for (int l = 0; l < kL; ++l) {
        ln_kernel<<<kM, 256, 0, stream>>>(X, ln1w + l * kC, ln1b + l * kC, Hbuf, nullptr, 0);
        gemm_bf16<2, 2, 4, 4, 0, 1><<<dim3(8, 32, 3), 256, 0, stream>>>(
            Hbuf, 0L, WQKVT + (long)l * 3 * kC * kC, (long)kC * kC,
            BQKV + l * 3 * kC, kC, QKV, (long)kM * kC, nullptr,
            kC, kC, kC, kC);
        attn_fused<<<dim3(512), 512, 0, stream>>>(
            QKV, QKV + (long)kM * kC, QKV + 2L * kM * kC, Y,
            attm_base + (long)l * kH * kT * kT);
        gemm_bf16<2, 2, 4, 4, 4, 1><<<dim3(8, 32, 1), 256, 0, stream>>>(
            Y, 0L, WOT + (long)l * kC * kC, 0L, bo + l * kC, 0,
            nullptr, 0L, X, kC, kC, kC, kC);
        ln_kernel<<<kM, 256, 0, stream>>>(X, ln2w + l * kC, ln2b + l * kC, Hbuf, nullptr, 0);
        gemm_bf16<2, 2, 1, 2, 3, 0><<<dim3(2, 128, 1), 256, 0, stream>>>(
            Hbuf, 0L, W1T + (long)l * kFFP * kC, 0L, b1 + l * kFF, 0,
            F1, 0L, nullptr, kFFP, kC, kC, kC);
        gemm_bf16<2, 2, 4, 4, 4, 1><<<dim3(8, 32, 1), 256, 0, stream>>>(
            F1, 0L, W2T + (long)l * kC * kFFP, 0L, b2 + l * kC, 0,
            nullptr, 0L, X, kC, kFFP, kFFP, kFFP);
    }
    ln_kernel<<<kM, 256, 0, stream>>>(X, lnfw, lnfb, nullptr, XF, 1);
    pool_kernel<<<dim3(4, kB, 8), 256, 0, stream>>>(XF, pooled);
}

// Round 7
// 1046.596 us; speedup vs baseline: 2.3372x; 2.3372x over previous
//
#include <hip/hip_runtime.h>

typedef __bf16 bf16;
typedef __bf16 bf16x4 __attribute__((ext_vector_type(4)));
typedef __bf16 bf16x8 __attribute__((ext_vector_type(8)));
typedef float  f32x4  __attribute__((ext_vector_type(4)));

static constexpr int kC   = 1024;
static constexpr int kT   = 1024;
static constexpr int kB   = 4;
static constexpr int kH   = 16;
static constexpr int kHD  = 64;
static constexpr int kL   = 4;
static constexpr int kFF  = 100;
static constexpr int kFFP = 128;
static constexpr int kM   = kB * kT;

__device__ __forceinline__ void gload16(const bf16* g, bf16* l)
{
    __builtin_amdgcn_global_load_lds(
        (const __attribute__((address_space(1))) void*)g,
        (__attribute__((address_space(3))) void*)l, 16, 0, 0);
}

__device__ __forceinline__ unsigned bpack(float a, float b)
{
    bf16 x = (bf16)a, y = (bf16)b;
    unsigned short ux = __builtin_bit_cast(unsigned short, x);
    unsigned short uy = __builtin_bit_cast(unsigned short, y);
    return (unsigned)ux | ((unsigned)uy << 16);
}
__device__ __forceinline__ float blo(unsigned u) { return __builtin_bit_cast(float, u << 16); }
__device__ __forceinline__ float bhi(unsigned u) { return __builtin_bit_cast(float, u & 0xffff0000u); }

// ---------------------------------------------------------------------------
__global__ __launch_bounds__(256)
void trans_cvt(const float* __restrict__ src, long sStride,
               bf16* __restrict__ dst, long dStride,
               int K, int N, int KP, int NP)
{
    __shared__ float tile[32][33];
    const int z = blockIdx.z;
    src += (long)z * sStride;
    dst += (long)z * dStride;
    const int n0 = blockIdx.x * 32, k0 = blockIdx.y * 32;
    const int tx = threadIdx.x & 31, ty = threadIdx.x >> 5;
#pragma unroll
    for (int i = 0; i < 4; ++i) {
        int k = k0 + ty + i * 8, n = n0 + tx;
        tile[ty + i * 8][tx] = (k < K && n < N) ? src[(long)k * N + n] : 0.f;
    }
    __syncthreads();
#pragma unroll
    for (int i = 0; i < 4; ++i) {
        int n = n0 + ty + i * 8, k = k0 + tx;
        if (n < NP && k < KP) dst[(long)n * KP + k] = (bf16)tile[tx][ty + i * 8];
    }
}

__global__ __launch_bounds__(256)
void pack_bias(const float* __restrict__ bq, const float* __restrict__ bk,
               const float* __restrict__ bv, float* __restrict__ dst)
{
    int gid = blockIdx.x * 256 + threadIdx.x;
    int l = gid / (3 * kC), w = (gid / kC) % 3, c = gid & (kC - 1);
    const float* s = (w == 0) ? bq : (w == 1) ? bk : bv;
    dst[gid] = s[l * kC + c];
}

__global__ __launch_bounds__(256)
void zero_kernel(float* __restrict__ p, int n)
{
    int i = blockIdx.x * 256 + threadIdx.x;
    if (i < n) p[i] = 0.f;
}

__global__ __launch_bounds__(256)
void embed_kernel(const int* __restrict__ idx, const float* __restrict__ tok,
                  const float* __restrict__ pos, float* __restrict__ x)
{
    const int m = blockIdx.x;
    const int c = threadIdx.x * 4;
    const int t = m & (kT - 1);
    const long tk = (long)idx[m] * kC;
    float4 a = *(const float4*)&tok[tk + c];
    float4 b = *(const float4*)&pos[(long)t * kC + c];
    float4 o; o.x = a.x + b.x; o.y = a.y + b.y; o.z = a.z + b.z; o.w = a.w + b.w;
    *(float4*)&x[(long)m * kC + c] = o;
}

__global__ __launch_bounds__(256)
void ln_kernel(const float* __restrict__ x, const float* __restrict__ g,
               const float* __restrict__ be, bf16* __restrict__ ob,
               float* __restrict__ of, int outf32)
{
    __shared__ float red[8];
    const long row = blockIdx.x;
    const int tid = threadIdx.x, lane = tid & 63, wv = tid >> 6;
    const float4 v = *(const float4*)&x[row * kC + tid * 4];
    float s = v.x + v.y + v.z + v.w;
    float s2 = v.x * v.x + v.y * v.y + v.z * v.z + v.w * v.w;
#pragma unroll
    for (int o = 32; o > 0; o >>= 1) { s += __shfl_down(s, o); s2 += __shfl_down(s2, o); }
    if (!lane) { red[wv] = s; red[4 + wv] = s2; }
    __syncthreads();
    s  = red[0] + red[1] + red[2] + red[3];
    s2 = red[4] + red[5] + red[6] + red[7];
    const float mean = s * (1.f / kC);
    const float var  = s2 * (1.f / kC) - mean * mean;
    const float rstd = rsqrtf(var + 1e-5f);
    const float4 gg = *(const float4*)&g[tid * 4];
    const float4 bb = *(const float4*)&be[tid * 4];
    float o0 = (v.x - mean) * rstd * gg.x + bb.x;
    float o1 = (v.y - mean) * rstd * gg.y + bb.y;
    float o2 = (v.z - mean) * rstd * gg.z + bb.z;
    float o3 = (v.w - mean) * rstd * gg.w + bb.w;
    if (outf32) {
        float4 o; o.x = o0; o.y = o1; o.z = o2; o.w = o3;
        *(float4*)&of[row * kC + tid * 4] = o;
    } else {
        bf16x4 o; o[0] = (bf16)o0; o[1] = (bf16)o1; o[2] = (bf16)o2; o[3] = (bf16)o3;
        *(bf16x4*)&ob[row * kC + tid * 4] = o;
    }
}

// ---------------------------------------------------------------------------
// MFMA GEMM (unchanged, proven): C = A * B^T.
// MODE 0: QKV (z=0 q*0.125 -> [B,H,T,HD]; z=1 k; z=2 v -> VT [B,H,HD,T])
// MODE 3: relu(acc+bias) ; MODE 4: resid += acc+bias
// ---------------------------------------------------------------------------
template<int WAVES_M, int WAVES_N, int AI, int BJ, int MODE, int GL>
__global__ __launch_bounds__(256)
void gemm_bf16(const bf16* __restrict__ Ag, long strideA,
               const bf16* __restrict__ Bg, long strideB,
               const float* __restrict__ bias, int strideBias,
               bf16* __restrict__ outb, long strideOut,
               float* __restrict__ resid,
               int N, int K, int lda, int ldb)
{
    constexpr int BM = WAVES_M * AI * 16;
    constexpr int BN = WAVES_N * BJ * 16;
    constexpr int BK = 64;
    constexpr int LK = GL ? BK : (BK + 8);
    __shared__ __align__(16) bf16 As[BM * LK];
    __shared__ __align__(16) bf16 Bs[BN * LK];
    const int tid = threadIdx.x, lane = tid & 63, wv = tid >> 6;
    const int wm = wv / WAVES_N, wn = wv % WAVES_N;
    const int lr = lane & 15, lg = lane >> 4;
    const int z = blockIdx.z;
    const bf16* A = Ag + (long)z * strideA;
    const bf16* B = Bg + (long)z * strideB;
    const float* bi = bias ? bias + (long)z * strideBias : nullptr;
    const int m0 = blockIdx.y * BM, n0 = blockIdx.x * BN;

    f32x4 acc[AI][BJ];
#pragma unroll
    for (int i = 0; i < AI; ++i)
#pragma unroll
        for (int j = 0; j < BJ; ++j) acc[i][j] = (f32x4){0.f, 0.f, 0.f, 0.f};

    for (int k0 = 0; k0 < K; k0 += BK) {
        if constexpr (GL) {
            static_assert(BM == 128 && BN == 128, "GL path needs 128x128 tile");
            const int srow = wv * 32 + (lane >> 3);
            const int gcb  = (lane & 7) ^ (lane >> 3);
#pragma unroll
            for (int p = 0; p < 4; ++p) {
                gload16(A + (long)(m0 + srow + p * 8) * lda + k0 + gcb * 8,
                        &As[(wv * 32 + p * 8) * BK]);
                gload16(B + (long)(n0 + srow + p * 8) * ldb + k0 + gcb * 8,
                        &Bs[(wv * 32 + p * 8) * BK]);
            }
        } else {
            constexpr int AP = (BM * BK) / (256 * 8);
#pragma unroll
            for (int p = 0; p < AP; ++p) {
                int r = p * 32 + (tid >> 3), c = (tid & 7) * 8;
                *(uint4*)&As[r * LK + c] = *(const uint4*)&A[(long)(m0 + r) * lda + k0 + c];
            }
            constexpr int BP = (BN * BK) / (256 * 8);
#pragma unroll
            for (int p = 0; p < BP; ++p) {
                int r = p * 32 + (tid >> 3), c = (tid & 7) * 8;
                *(uint4*)&Bs[r * LK + c] = *(const uint4*)&B[(long)(n0 + r) * ldb + k0 + c];
            }
        }
        __syncthreads();
#pragma unroll
        for (int kk = 0; kk < 2; ++kk) {
            bf16x8 af[AI], bfv[BJ];
#pragma unroll
            for (int i = 0; i < AI; ++i) {
                const int r = wm * AI * 16 + i * 16 + lr;
                const int c = GL ? (((kk * 4 + lg) ^ (lr & 7)) * 8) : (kk * 32 + lg * 8);
                af[i] = *(const bf16x8*)&As[r * LK + c];
            }
#pragma unroll
            for (int j = 0; j < BJ; ++j) {
                const int r = wn * BJ * 16 + j * 16 + lr;
                const int c = GL ? (((kk * 4 + lg) ^ (lr & 7)) * 8) : (kk * 32 + lg * 8);
                bfv[j] = *(const bf16x8*)&Bs[r * LK + c];
            }
#pragma unroll
            for (int i = 0; i < AI; ++i)
#pragma unroll
                for (int j = 0; j < BJ; ++j)
                    acc[i][j] = __builtin_amdgcn_mfma_f32_16x16x32_bf16(af[i], bfv[j], acc[i][j], 0, 0, 0);
        }
        __syncthreads();
    }

#pragma unroll
    for (int i = 0; i < AI; ++i)
#pragma unroll
        for (int j = 0; j < BJ; ++j)
#pragma unroll
            for (int rr = 0; rr < 4; ++rr) {
                const int grow = m0 + wm * AI * 16 + i * 16 + lg * 4 + rr;
                const int gcol = n0 + wn * BJ * 16 + j * 16 + lr;
                float v = acc[i][j][rr];
                if constexpr (MODE == 0) {
                    v += bi[gcol];
                    if (z == 0) v *= 0.125f;   // fold attention scale into Q
                    const int b = grow >> 10, t = grow & (kT - 1);
                    const int hh = gcol >> 6, hd = gcol & 63;
                    long o = (long)z * strideOut;
                    if (z == 2) o += (((long)b * kH + hh) * kHD + hd) * kT + t;  // VT
                    else        o += (((long)b * kH + hh) * kT + t) * kHD + hd;  // Q/K
                    outb[o] = (bf16)v;
                } else if constexpr (MODE == 3) {
                    v += (gcol < kFF) ? bi[gcol] : 0.f;
                    outb[(long)grow * N + gcol] = (bf16)fmaxf(v, 0.f);
                } else {
                    v += bi[gcol];
                    resid[(long)grow * N + gcol] += v;
                }
            }
}

// ---------------------------------------------------------------------------
// Fused attention v7: swapped QK^T (mfma(K,Q) -> lane col=q), no max-sub,
// two 64-col halves (acc 32 regs), E packed bf16x2 -> Ps via ds_write_b64,
// per-lane row sums + xor16/xor32 + one cross-wave LDS reduce, am (attm
// accumulator) packed bf16x2 in 32 regs updated from Ps read-back, PV as
// proven R5 (swizzled Ps reads + direct-L2 V). 2 barriers per b.
// launch_bounds(512,2): cap 128 VGPR -> 2 blocks/CU. LDS ~65 KB.
// ---------------------------------------------------------------------------
__global__ __launch_bounds__(512, 2)
void attn_fused(const bf16* __restrict__ Qg, const bf16* __restrict__ Kg,
                const bf16* __restrict__ VTg, bf16* __restrict__ yg,
                float* __restrict__ attm)
{
    __shared__ __align__(16) bf16 Ps[32 * kT];    // 64 KB; epilogue: fp32 [32][512]
    __shared__ float reds[32][8];
    __shared__ float invs[32];
    const int tid = threadIdx.x, lane = tid & 63, w = tid >> 6;
    const int lr = lane & 15, lg = lane >> 4;
    const int bid = blockIdx.x, r_ = bid >> 3;
    const int h = ((bid & 7) << 1) | (r_ & 1);    // XCD-local head
    const int q0 = (r_ >> 1) * 32;
    const int rh = w >> 2, ch = w & 3;            // PV: wave = one 16x16 y tile

    // per-thread Ps element-offsets (bf16 units) for its 16 (half,j,qt) b64 slots
    // q = qt*16+lr ; t = w*128 + half*64 + j*16 + lg*4 + {0..3}
    // elem = q*1024 + ((t>>3)^(q&7))*8 + (t&7);  b64 covers 4 bf16 (d=0,1)
    const int tbB = w * 16 + (lg >> 1);           // t>>3 for half=0,j=0
    const int loB = (lg & 1) * 4;                 // (t&7) base (d spans +0..3)
    unsigned am_[2][4][2][2];                     // attm acc, bf16x2-packed
#pragma unroll
    for (int hf = 0; hf < 2; ++hf)
#pragma unroll
        for (int j = 0; j < 4; ++j)
#pragma unroll
            for (int qt = 0; qt < 2; ++qt)
#pragma unroll
                for (int d = 0; d < 2; ++d) am_[hf][j][qt][d] = 0u;

    for (int b = 0; b < kB; ++b) {
        const long bh = (long)b * kH + h;
        const bf16* Qb = Qg + (bh * kT + q0) * kHD;
        const bf16* Kb = Kg + bh * kT * kHD;
        const bf16* Vb = VTg + bh * (long)kHD * kT;

        if (b) __syncthreads();   // prior-b PV Ps reads done before rewrite

        // Q B-fragments (col = q = lr within tile), k-contig over hd
        bf16x8 qf[2][2];
#pragma unroll
        for (int qt = 0; qt < 2; ++qt)
#pragma unroll
            for (int kk = 0; kk < 2; ++kk)
                qf[qt][kk] = *(const bf16x8*)&Qb[(long)(qt * 16 + lr) * kHD + kk * 32 + lg * 8];

        float s[2] = {0.f, 0.f};  // per-lane partial row sums (q = qt*16+lr)

#pragma unroll
        for (int hf = 0; hf < 2; ++hf) {
            // QK^T swapped: acc[j][qt] holds S[t][q], t = w*128+hf*64+j*16+lg*4+r
            f32x4 acc[4][2];
#pragma unroll
            for (int j = 0; j < 4; ++j)
#pragma unroll
                for (int qt = 0; qt < 2; ++qt) acc[j][qt] = (f32x4){0.f, 0.f, 0.f, 0.f};
#pragma unroll
            for (int j = 0; j < 4; ++j) {
                const int trow = w * 128 + hf * 64 + j * 16 + lr;
#pragma unroll
                for (int kk = 0; kk < 2; ++kk) {
                    const bf16x8 kf = *(const bf16x8*)&Kb[(long)trow * kHD + kk * 32 + lg * 8];
                    acc[j][0] = __builtin_amdgcn_mfma_f32_16x16x32_bf16(kf, qf[0][kk], acc[j][0], 0, 0, 0);
                    acc[j][1] = __builtin_amdgcn_mfma_f32_16x16x32_bf16(kf, qf[1][kk], acc[j][1], 0, 0, 0);
                }
            }
            // exp, sum, pack -> Ps (b64 per (j,qt))
#pragma unroll
            for (int j = 0; j < 4; ++j) {
                const int tb = tbB + hf * 8 + j * 2;
#pragma unroll
                for (int qt = 0; qt < 2; ++qt) {
                    float e0 = __expf(acc[j][qt][0]);
                    float e1 = __expf(acc[j][qt][1]);
                    float e2 = __expf(acc[j][qt][2]);
                    float e3 = __expf(acc[j][qt][3]);
                    s[qt] += (e0 + e1) + (e2 + e3);
                    const int q = qt * 16 + lr;
                    uint2 pk; pk.x = bpack(e0, e1); pk.y = bpack(e2, e3);
                    *(uint2*)&Ps[q * kT + ((tb ^ (q & 7)) << 3) + loB] = pk;
                }
            }
        }

        // cross-lane (lg groups) then cross-wave row sums
#pragma unroll
        for (int qt = 0; qt < 2; ++qt) {
            s[qt] += __shfl_xor(s[qt], 16);
            s[qt] += __shfl_xor(s[qt], 32);
        }
        if (lane < 16) { reds[lane][w] = s[0]; reds[16 + lane][w] = s[1]; }
        __syncthreads();   // (1) Ps + reds visible

        float inv[2], iv4[2];
#pragma unroll
        for (int qt = 0; qt < 2; ++qt) {
            const int q = qt * 16 + lr;
            float4 a = *(const float4*)&reds[q][0];
            float4 c = *(const float4*)&reds[q][4];
            float tot = ((a.x + a.y) + (a.z + a.w)) + ((c.x + c.y) + (c.z + c.w));
            inv[qt] = __builtin_amdgcn_rcpf(tot);
            iv4[qt] = inv[qt] * 0.25f;
        }
        if (lane < 16) { invs[lane] = inv[0]; invs[16 + lane] = inv[1]; }  // benign identical-value race

        // am += E * inv/4  (read back own E dwords from Ps)
#pragma unroll
        for (int hf = 0; hf < 2; ++hf)
#pragma unroll
            for (int j = 0; j < 4; ++j) {
                const int tb = tbB + hf * 8 + j * 2;
#pragma unroll
                for (int qt = 0; qt < 2; ++qt) {
                    const int q = qt * 16 + lr;
                    uint2 e2 = *(const uint2*)&Ps[q * kT + ((tb ^ (q & 7)) << 3) + loB];
#pragma unroll
                    for (int d = 0; d < 2; ++d) {
                        unsigned ev = d ? e2.y : e2.x;
                        unsigned av = am_[hf][j][qt][d];
                        float n0 = blo(av) + blo(ev) * iv4[qt];
                        float n1 = bhi(av) + bhi(ev) * iv4[qt];
                        am_[hf][j][qt][d] = bpack(n0, n1);
                    }
                }
            }

        // PV (R5-proven): wave (rh,ch) computes y[rh*16..+15][ch*16..+15]
        f32x4 yacc = (f32x4){0.f, 0.f, 0.f, 0.f};
        const int rowA = rh * 16 + lr;
        const long dRow = (long)(ch * 16 + lr) * kT;
#pragma unroll 4
        for (int kb = 0; kb < 32; ++kb) {
            const bf16x8 a = *(const bf16x8*)&Ps[rowA * kT + (((kb * 4 + lg) ^ (rowA & 7)) << 3)];
            const bf16x8 v = *(const bf16x8*)&Vb[dRow + kb * 32 + lg * 8];
            yacc = __builtin_amdgcn_mfma_f32_16x16x32_bf16(a, v, yacc, 0, 0, 0);
        }
#pragma unroll
        for (int rr = 0; rr < 4; ++rr) {
            const float iv = invs[rh * 16 + lg * 4 + rr];
            yg[((long)b * kT + q0 + rh * 16 + lg * 4 + rr) * kC + h * kHD + ch * 16 + lr]
                = (bf16)(yacc[rr] * iv);
        }
    }

    __syncthreads();   // all PV reads done before fp32 reuse of Ps
    // attm epilogue: two t-halves staged through fp32 [32][512] in Ps region
    float* amf = (float*)Ps;
#pragma unroll
    for (int th = 0; th < 2; ++th) {
        if ((w >> 2) == th) {   // waves whose t-range lies in this half
#pragma unroll
            for (int hf = 0; hf < 2; ++hf)
#pragma unroll
                for (int j = 0; j < 4; ++j) {
                    const int tl = (w & 3) * 128 + hf * 64 + j * 16 + lg * 4;
#pragma unroll
                    for (int qt = 0; qt < 2; ++qt) {
                        const int q = qt * 16 + lr;
#pragma unroll
                        for (int d = 0; d < 2; ++d) {
                            unsigned av = am_[hf][j][qt][d];
                            amf[q * 512 + tl + 2 * d]     = blo(av);
                            amf[q * 512 + tl + 2 * d + 1] = bhi(av);
                        }
                    }
                }
        }
        __syncthreads();
#pragma unroll
        for (int p = 0; p < 8; ++p) {
            const int f = p * 512 + tid;            // 4096 float4s
            const int row = f >> 7, c4 = f & 127;
            float4 v = *(const float4*)&amf[row * 512 + c4 * 4];
            *(float4*)&attm[((long)h * kT + q0 + row) * kT + th * 512 + c4 * 4] = v;
        }
        __syncthreads();
    }
}

__global__ __launch_bounds__(256)
void pool_kernel(const float* __restrict__ xf, float* __restrict__ pooled)
{
    const int c = blockIdx.x * 256 + threadIdx.x;
    const int b = blockIdx.y;
    const int t0 = blockIdx.z * 128;
    float s = 0.f;
    for (int t = t0; t < t0 + 128; ++t) s += xf[((long)b * kT + t) * kC + c];
    atomicAdd(&pooled[b * kC + c], s * (1.f / kT));
}

// ---------------------------------------------------------------------------
extern "C" void kernel_launch(void* const* d_in, const int* in_sizes, int n_in,
                              void* d_out, int out_size, void* d_ws, size_t ws_size,
                              hipStream_t stream)
{
    const int*   idx  = (const int*)d_in[0];
    const float* tok  = (const float*)d_in[1];
    const float* pos  = (const float*)d_in[2];
    const float* Wq   = (const float*)d_in[3];
    const float* bq   = (const float*)d_in[4];
    const float* Wk   = (const float*)d_in[5];
    const float* bk   = (const float*)d_in[6];
    const float* Wv   = (const float*)d_in[7];
    const float* bv   = (const float*)d_in[8];
    const float* Wo   = (const float*)d_in[9];
    const float* bo   = (const float*)d_in[10];
    const float* ln1w = (const float*)d_in[11];
    const float* ln1b = (const float*)d_in[12];
    const float* ln2w = (const float*)d_in[13];
    const float* ln2b = (const float*)d_in[14];
    const float* W1   = (const float*)d_in[15];
    const float* b1   = (const float*)d_in[16];
    const float* W2   = (const float*)d_in[17];
    const float* b2   = (const float*)d_in[18];
    const float* lnfw = (const float*)d_in[19];
    const float* lnfb = (const float*)d_in[20];

    char* ws = (char*)d_ws;
    long off = 0;
    auto alloc = [&](long bytes) { char* p = ws + off; off += (bytes + 255) & ~255L; return p; };
    bf16*  WQKVT = (bf16*)alloc((long)kL * 3 * kC * kC * 2);
    bf16*  WOT   = (bf16*)alloc((long)kL * kC * kC * 2);
    bf16*  W1T   = (bf16*)alloc((long)kL * kFFP * kC * 2);
    bf16*  W2T   = (bf16*)alloc((long)kL * kC * kFFP * 2);
    float* BQKV  = (float*)alloc((long)kL * 3 * kC * 4);
    float* X     = (float*)alloc((long)kM * kC * 4);
    bf16*  Hbuf  = (bf16*)alloc((long)kM * kC * 2);
    bf16*  QKV   = (bf16*)alloc(3L * kM * kC * 2);
    bf16*  Y     = (bf16*)alloc((long)kM * kC * 2);
    bf16*  F1    = (bf16*)alloc((long)kM * kFFP * 2);
    float* XF    = (float*)alloc((long)kM * kC * 4);

    float* pooled = (float*)d_out;
    float* attm_base = pooled + kB * kC;

    zero_kernel<<<16, 256, 0, stream>>>(pooled, kB * kC);
    dim3 tg(32, 32, kL);
    trans_cvt<<<tg, 256, 0, stream>>>(Wq, (long)kC * kC, WQKVT + 0L * kC * kC, 3L * kC * kC, kC, kC, kC, kC);
    trans_cvt<<<tg, 256, 0, stream>>>(Wk, (long)kC * kC, WQKVT + 1L * kC * kC, 3L * kC * kC, kC, kC, kC, kC);
    trans_cvt<<<tg, 256, 0, stream>>>(Wv, (long)kC * kC, WQKVT + 2L * kC * kC, 3L * kC * kC, kC, kC, kC, kC);
    trans_cvt<<<tg, 256, 0, stream>>>(Wo, (long)kC * kC, WOT, (long)kC * kC, kC, kC, kC, kC);
    trans_cvt<<<dim3(4, 32, kL), 256, 0, stream>>>(W1, (long)kC * kFF, W1T, (long)kFFP * kC, kC, kFF, kC, kFFP);
    trans_cvt<<<dim3(32, 4, kL), 256, 0, stream>>>(W2, (long)kFF * kC, W2T, (long)kC * kFFP, kFF, kC, kFFP, kC);
    pack_bias<<<48, 256, 0, stream>>>(bq, bk, bv, BQKV);

    embed_kernel<<<kM, 256, 0, stream>>>(idx, tok, pos, X);

    for (int l = 0; l < kL; ++l) {
        ln_kernel<<<kM, 256, 0, stream>>>(X, ln1w + l * kC, ln1b + l * kC, Hbuf, nullptr, 0);
        gemm_bf16<2, 2, 4, 4, 0, 1><<<dim3(8, 32, 3), 256, 0, stream>>>(
            Hbuf, 0L, WQKVT + (long)l * 3 * kC * kC, (long)kC * kC,
            BQKV + l * 3 * kC, kC, QKV, (long)kM * kC, nullptr,
            kC, kC, kC, kC);
        attn_fused<<<dim3(512), 512, 0, stream>>>(
            QKV, QKV + (long)kM * kC, QKV + 2L * kM * kC, Y,
            attm_base + (long)l * kH * kT * kT);
        gemm_bf16<2, 2, 4, 4, 4, 1><<<dim3(8, 32, 1), 256, 0, stream>>>(
            Y, 0L, WOT + (long)l * kC * kC, 0L, bo + l * kC, 0,
            nullptr, 0L, X, kC, kC, kC, kC);
        ln_kernel<<<kM, 256, 0, stream>>>(X, ln2w + l * kC, ln2b + l * kC, Hbuf, nullptr, 0);
        gemm_bf16<2, 2, 1, 2, 3, 0><<<dim3(2, 128, 1), 256, 0, stream>>>(
            Hbuf, 0L, W1T + (long)l * kFFP * kC, 0L, b1 + l * kFF, 0,
            F1, 0L, nullptr, kFFP, kC, kC, kC);
        gemm_bf16<2, 2, 4, 4, 4, 1><<<dim3(8, 32, 1), 256, 0, stream>>>(
            F1, 0L, W2T + (long)l * kC * kFFP, 0L, b2 + l * kC, 0,
            nullptr, 0L, X, kC, kFFP, kFFP, kFFP);
    }
    ln_kernel<<<kM, 256, 0, stream>>>(X, lnfw, lnfb, nullptr, XF, 1);
    pool_kernel<<<dim3(4, kB, 8), 256, 0, stream>>>(XF, pooled);
}

// Round 8
// 991.183 us; speedup vs baseline: 2.4678x; 1.0559x over previous
//
#include <hip/hip_runtime.h>

typedef __bf16 bf16;
typedef __bf16 bf16x4 __attribute__((ext_vector_type(4)));
typedef __bf16 bf16x8 __attribute__((ext_vector_type(8)));
typedef float  f32x4  __attribute__((ext_vector_type(4)));

static constexpr int kC   = 1024;
static constexpr int kT   = 1024;
static constexpr int kB   = 4;
static constexpr int kH   = 16;
static constexpr int kHD  = 64;
static constexpr int kL   = 4;
static constexpr int kFF  = 100;
static constexpr int kFFP = 128;
static constexpr int kM   = kB * kT;

__device__ __forceinline__ void gload16(const bf16* g, bf16* l)
{
    __builtin_amdgcn_global_load_lds(
        (const __attribute__((address_space(1))) void*)g,
        (__attribute__((address_space(3))) void*)l, 16, 0, 0);
}

__device__ __forceinline__ unsigned bpack(float a, float b)
{
    bf16 x = (bf16)a, y = (bf16)b;
    unsigned short ux = __builtin_bit_cast(unsigned short, x);
    unsigned short uy = __builtin_bit_cast(unsigned short, y);
    return (unsigned)ux | ((unsigned)uy << 16);
}
__device__ __forceinline__ float blo(unsigned u) { return __builtin_bit_cast(float, u << 16); }
__device__ __forceinline__ float bhi(unsigned u) { return __builtin_bit_cast(float, u & 0xffff0000u); }

// ---------------------------------------------------------------------------
// One-shot prep: all weight transposes/converts + bias pack + pooled zero.
// Flat grid 17472 blocks, branch-decoded.
// ---------------------------------------------------------------------------
__global__ __launch_bounds__(256)
void prep_kernel(const float* __restrict__ Wq, const float* __restrict__ Wk,
                 const float* __restrict__ Wv, const float* __restrict__ Wo,
                 const float* __restrict__ W1, const float* __restrict__ W2,
                 const float* __restrict__ bq, const float* __restrict__ bk,
                 const float* __restrict__ bv,
                 bf16* __restrict__ WQKVT, bf16* __restrict__ WOT,
                 bf16* __restrict__ W1T, bf16* __restrict__ W2T,
                 float* __restrict__ BQKV, float* __restrict__ pooled)
{
    __shared__ float tile[32][33];
    const int bid = blockIdx.x, tid = threadIdx.x;
    const float* src; bf16* dst; int K, N, KP, NP, bx, by;
    if (bid < 12288) {                       // Wq/Wk/Wv -> WQKVT[l][which]
        const int slab = bid >> 10, within = bid & 1023;
        const int l = slab / 3, which = slab % 3;
        const float* W = (which == 0) ? Wq : (which == 1) ? Wk : Wv;
        src = W + (long)l * kC * kC;
        dst = WQKVT + (long)l * 3 * kC * kC + (long)which * kC * kC;
        K = N = KP = NP = kC; bx = within & 31; by = within >> 5;
    } else if (bid < 16384) {                // Wo -> WOT
        const int t = bid - 12288, z = t >> 10, within = t & 1023;
        src = Wo + (long)z * kC * kC; dst = WOT + (long)z * kC * kC;
        K = N = KP = NP = kC; bx = within & 31; by = within >> 5;
    } else if (bid < 16896) {                // W1 -> W1T (N=100 -> NP=128)
        const int t = bid - 16384, z = t >> 7, within = t & 127;
        src = W1 + (long)z * kC * kFF; dst = W1T + (long)z * kFFP * kC;
        K = kC; N = kFF; KP = kC; NP = kFFP; bx = within & 3; by = within >> 2;
    } else if (bid < 17408) {                // W2 -> W2T (K=100 -> KP=128)
        const int t = bid - 16896, z = t >> 7, within = t & 127;
        src = W2 + (long)z * kFF * kC; dst = W2T + (long)z * kC * kFFP;
        K = kFF; N = kC; KP = kFFP; NP = kC; bx = within & 31; by = within >> 5;
    } else if (bid < 17456) {                // bias pack
        const int gid = (bid - 17408) * 256 + tid;
        const int l = gid / (3 * kC), wq = (gid / kC) % 3, c = gid & (kC - 1);
        const float* s = (wq == 0) ? bq : (wq == 1) ? bk : bv;
        BQKV[gid] = s[l * kC + c];
        return;
    } else {                                 // zero pooled
        const int i = (bid - 17456) * 256 + tid;
        if (i < kB * kC) pooled[i] = 0.f;
        return;
    }
    const int n0 = bx * 32, k0 = by * 32;
    const int tx = tid & 31, ty = tid >> 5;
#pragma unroll
    for (int i = 0; i < 4; ++i) {
        int k = k0 + ty + i * 8, n = n0 + tx;
        tile[ty + i * 8][tx] = (k < K && n < N) ? src[(long)k * N + n] : 0.f;
    }
    __syncthreads();
#pragma unroll
    for (int i = 0; i < 4; ++i) {
        int n = n0 + ty + i * 8, k = k0 + tx;
        if (n < NP && k < KP) dst[(long)n * KP + k] = (bf16)tile[tx][ty + i * 8];
    }
}

__global__ __launch_bounds__(256)
void embed_kernel(const int* __restrict__ idx, const float* __restrict__ tok,
                  const float* __restrict__ pos, float* __restrict__ x)
{
    const int m = blockIdx.x;
    const int c = threadIdx.x * 4;
    const int t = m & (kT - 1);
    const long tk = (long)idx[m] * kC;
    float4 a = *(const float4*)&tok[tk + c];
    float4 b = *(const float4*)&pos[(long)t * kC + c];
    float4 o; o.x = a.x + b.x; o.y = a.y + b.y; o.z = a.z + b.z; o.w = a.w + b.w;
    *(float4*)&x[(long)m * kC + c] = o;
}

__global__ __launch_bounds__(256)
void ln_kernel(const float* __restrict__ x, const float* __restrict__ g,
               const float* __restrict__ be, bf16* __restrict__ ob,
               float* __restrict__ of, int outf32)
{
    __shared__ float red[8];
    const long row = blockIdx.x;
    const int tid = threadIdx.x, lane = tid & 63, wv = tid >> 6;
    const float4 v = *(const float4*)&x[row * kC + tid * 4];
    float s = v.x + v.y + v.z + v.w;
    float s2 = v.x * v.x + v.y * v.y + v.z * v.z + v.w * v.w;
#pragma unroll
    for (int o = 32; o > 0; o >>= 1) { s += __shfl_down(s, o); s2 += __shfl_down(s2, o); }
    if (!lane) { red[wv] = s; red[4 + wv] = s2; }
    __syncthreads();
    s  = red[0] + red[1] + red[2] + red[3];
    s2 = red[4] + red[5] + red[6] + red[7];
    const float mean = s * (1.f / kC);
    const float var  = s2 * (1.f / kC) - mean * mean;
    const float rstd = rsqrtf(var + 1e-5f);
    const float4 gg = *(const float4*)&g[tid * 4];
    const float4 bb = *(const float4*)&be[tid * 4];
    float o0 = (v.x - mean) * rstd * gg.x + bb.x;
    float o1 = (v.y - mean) * rstd * gg.y + bb.y;
    float o2 = (v.z - mean) * rstd * gg.z + bb.z;
    float o3 = (v.w - mean) * rstd * gg.w + bb.w;
    if (outf32) {
        float4 o; o.x = o0; o.y = o1; o.z = o2; o.w = o3;
        *(float4*)&of[row * kC + tid * 4] = o;
    } else {
        bf16x4 o; o[0] = (bf16)o0; o[1] = (bf16)o1; o[2] = (bf16)o2; o[3] = (bf16)o3;
        *(bf16x4*)&ob[row * kC + tid * 4] = o;
    }
}

// ---------------------------------------------------------------------------
// MFMA GEMM (proven): C = A * B^T.  GL=1: global_load_lds, 128x128 tile.
// MODE 0: QKV (z=0 q*0.125*log2e -> [B,H,T,HD]; z=1 k; z=2 v -> VT)
// MODE 4: resid += acc + bias
// ---------------------------------------------------------------------------
template<int WAVES_M, int WAVES_N, int AI, int BJ, int MODE, int GL>
__global__ __launch_bounds__(256)
void gemm_bf16(const bf16* __restrict__ Ag, long strideA,
               const bf16* __restrict__ Bg, long strideB,
               const float* __restrict__ bias, int strideBias,
               bf16* __restrict__ outb, long strideOut,
               float* __restrict__ resid,
               int N, int K, int lda, int ldb)
{
    constexpr int BM = WAVES_M * AI * 16;
    constexpr int BN = WAVES_N * BJ * 16;
    constexpr int BK = 64;
    constexpr int LK = GL ? BK : (BK + 8);
    __shared__ __align__(16) bf16 As[BM * LK];
    __shared__ __align__(16) bf16 Bs[BN * LK];
    const int tid = threadIdx.x, lane = tid & 63, wv = tid >> 6;
    const int wm = wv / WAVES_N, wn = wv % WAVES_N;
    const int lr = lane & 15, lg = lane >> 4;
    const int z = blockIdx.z;
    const bf16* A = Ag + (long)z * strideA;
    const bf16* B = Bg + (long)z * strideB;
    const float* bi = bias ? bias + (long)z * strideBias : nullptr;
    const int m0 = blockIdx.y * BM, n0 = blockIdx.x * BN;

    f32x4 acc[AI][BJ];
#pragma unroll
    for (int i = 0; i < AI; ++i)
#pragma unroll
        for (int j = 0; j < BJ; ++j) acc[i][j] = (f32x4){0.f, 0.f, 0.f, 0.f};

    for (int k0 = 0; k0 < K; k0 += BK) {
        if constexpr (GL) {
            static_assert(BM == 128 && BN == 128, "GL path needs 128x128 tile");
            const int srow = wv * 32 + (lane >> 3);
            const int gcb  = (lane & 7) ^ (lane >> 3);
#pragma unroll
            for (int p = 0; p < 4; ++p) {
                gload16(A + (long)(m0 + srow + p * 8) * lda + k0 + gcb * 8,
                        &As[(wv * 32 + p * 8) * BK]);
                gload16(B + (long)(n0 + srow + p * 8) * ldb + k0 + gcb * 8,
                        &Bs[(wv * 32 + p * 8) * BK]);
            }
        } else {
            constexpr int AP = (BM * BK) / (256 * 8);
#pragma unroll
            for (int p = 0; p < AP; ++p) {
                int r = p * 32 + (tid >> 3), c = (tid & 7) * 8;
                *(uint4*)&As[r * LK + c] = *(const uint4*)&A[(long)(m0 + r) * lda + k0 + c];
            }
            constexpr int BP = (BN * BK) / (256 * 8);
#pragma unroll
            for (int p = 0; p < BP; ++p) {
                int r = p * 32 + (tid >> 3), c = (tid & 7) * 8;
                *(uint4*)&Bs[r * LK + c] = *(const uint4*)&B[(long)(n0 + r) * ldb + k0 + c];
            }
        }
        __syncthreads();
#pragma unroll
        for (int kk = 0; kk < 2; ++kk) {
            bf16x8 af[AI], bfv[BJ];
#pragma unroll
            for (int i = 0; i < AI; ++i) {
                const int r = wm * AI * 16 + i * 16 + lr;
                const int c = GL ? (((kk * 4 + lg) ^ (lr & 7)) * 8) : (kk * 32 + lg * 8);
                af[i] = *(const bf16x8*)&As[r * LK + c];
            }
#pragma unroll
            for (int j = 0; j < BJ; ++j) {
                const int r = wn * BJ * 16 + j * 16 + lr;
                const int c = GL ? (((kk * 4 + lg) ^ (lr & 7)) * 8) : (kk * 32 + lg * 8);
                bfv[j] = *(const bf16x8*)&Bs[r * LK + c];
            }
#pragma unroll
            for (int i = 0; i < AI; ++i)
#pragma unroll
                for (int j = 0; j < BJ; ++j)
                    acc[i][j] = __builtin_amdgcn_mfma_f32_16x16x32_bf16(af[i], bfv[j], acc[i][j], 0, 0, 0);
        }
        __syncthreads();
    }

#pragma unroll
    for (int i = 0; i < AI; ++i)
#pragma unroll
        for (int j = 0; j < BJ; ++j)
#pragma unroll
            for (int rr = 0; rr < 4; ++rr) {
                const int grow = m0 + wm * AI * 16 + i * 16 + lg * 4 + rr;
                const int gcol = n0 + wn * BJ * 16 + j * 16 + lr;
                float v = acc[i][j][rr];
                if constexpr (MODE == 0) {
                    v += bi[gcol];
                    if (z == 0) v *= 0.125f * 1.44269504f;  // scale * log2(e)
                    const int b = grow >> 10, t = grow & (kT - 1);
                    const int hh = gcol >> 6, hd = gcol & 63;
                    long o = (long)z * strideOut;
                    if (z == 2) o += (((long)b * kH + hh) * kHD + hd) * kT + t;  // VT
                    else        o += (((long)b * kH + hh) * kT + t) * kHD + hd;  // Q/K
                    outb[o] = (bf16)v;
                } else {
                    v += bi[gcol];
                    resid[(long)grow * N + gcol] += v;
                }
            }
}

// ---------------------------------------------------------------------------
// Fused FF: ln2 + FF1(relu) + FF2(+=X), one block per 16 rows, 4 waves.
// Hs[16][1024] (swizzled bf16, ln2 output) 32 KB; F1s[16][128] 4 KB.
// W1T/W2T read direct from L2 (256 KB each, resident).
// ---------------------------------------------------------------------------
__global__ __launch_bounds__(256, 2)
void ff_fused(float* __restrict__ X, const float* __restrict__ g,
              const float* __restrict__ be,
              const bf16* __restrict__ W1T_, const float* __restrict__ b1_,
              const bf16* __restrict__ W2T_, const float* __restrict__ b2_)
{
    __shared__ __align__(16) bf16 Hs[16 * kC];
    __shared__ __align__(16) bf16 F1s[16 * kFFP];
    const int tid = threadIdx.x, lane = tid & 63, w = tid >> 6;
    const int lr = lane & 15, lg = lane >> 4;
    const int r0 = blockIdx.x * 16;

    // Phase A: ln2 on rows r0..r0+15 -> Hs (16B-block XOR swizzle by row&7)
    {
        const int row = tid >> 4, c16 = tid & 15;
        float4 xv[16];
        float s1 = 0.f, s2 = 0.f;
#pragma unroll
        for (int p = 0; p < 8; ++p) {
            const float* base = &X[(long)(r0 + row) * kC + p * 128 + c16 * 8];
            xv[2 * p]     = *(const float4*)base;
            xv[2 * p + 1] = *(const float4*)(base + 4);
#pragma unroll
            for (int e = 0; e < 4; ++e) {
                float a0 = ((const float*)&xv[2 * p])[e], a1 = ((const float*)&xv[2 * p + 1])[e];
                s1 += a0 + a1; s2 += a0 * a0 + a1 * a1;
            }
        }
#pragma unroll
        for (int off = 1; off < 16; off <<= 1) { s1 += __shfl_xor(s1, off); s2 += __shfl_xor(s2, off); }
        const float mean = s1 * (1.f / kC);
        const float rstd = rsqrtf(s2 * (1.f / kC) - mean * mean + 1e-5f);
#pragma unroll
        for (int p = 0; p < 8; ++p) {
            const int c0 = p * 128 + c16 * 8;
            float4 g0 = *(const float4*)&g[c0],  g1 = *(const float4*)&g[c0 + 4];
            float4 b0 = *(const float4*)&be[c0], b1v = *(const float4*)&be[c0 + 4];
            float h[8];
#pragma unroll
            for (int e = 0; e < 4; ++e) {
                h[e]     = (((const float*)&xv[2 * p])[e]     - mean) * rstd * ((const float*)&g0)[e] + ((const float*)&b0)[e];
                h[4 + e] = (((const float*)&xv[2 * p + 1])[e] - mean) * rstd * ((const float*)&g1)[e] + ((const float*)&b1v)[e];
            }
            uint4 hv;
            hv.x = bpack(h[0], h[1]); hv.y = bpack(h[2], h[3]);
            hv.z = bpack(h[4], h[5]); hv.w = bpack(h[6], h[7]);
            const int cb = c16 + p * 16;
            *(uint4*)&Hs[row * kC + ((cb ^ (row & 7)) << 3)] = hv;
        }
    }
    __syncthreads();

    // Phase B: FF1 f1[16][128] = relu(Hs @ W1T + b1) -> F1s (swizzled)
    {
        f32x4 acc[2];
        acc[0] = (f32x4){0.f, 0.f, 0.f, 0.f};
        acc[1] = (f32x4){0.f, 0.f, 0.f, 0.f};
        for (int k0 = 0; k0 < kC; k0 += 64) {
#pragma unroll
            for (int kk = 0; kk < 2; ++kk) {
                const bf16x8 a = *(const bf16x8*)&Hs[lr * kC + ((((k0 >> 3) + kk * 4 + lg) ^ (lr & 7)) << 3)];
#pragma unroll
                for (int j = 0; j < 2; ++j) {
                    const bf16x8 bv = *(const bf16x8*)&W1T_[(long)(w * 32 + j * 16 + lr) * kC + k0 + kk * 32 + lg * 8];
                    acc[j] = __builtin_amdgcn_mfma_f32_16x16x32_bf16(a, bv, acc[j], 0, 0, 0);
                }
            }
        }
#pragma unroll
        for (int j = 0; j < 2; ++j)
#pragma unroll
            for (int rr = 0; rr < 4; ++rr) {
                const int row = lg * 4 + rr, col = w * 32 + j * 16 + lr;
                float v = acc[j][rr] + (col < kFF ? b1_[col] : 0.f);
                F1s[row * kFFP + (((col >> 3) ^ (row & 7)) << 3) + (col & 7)] = (bf16)fmaxf(v, 0.f);
            }
    }
    __syncthreads();

    // Phase C: FF2  X[16][1024] += F1s @ W2T + b2   (8 n-chunks of 128)
    for (int nc = 0; nc < 8; ++nc) {
        f32x4 acc[2];
        acc[0] = (f32x4){0.f, 0.f, 0.f, 0.f};
        acc[1] = (f32x4){0.f, 0.f, 0.f, 0.f};
#pragma unroll
        for (int kk = 0; kk < 4; ++kk) {
            const bf16x8 a = *(const bf16x8*)&F1s[lr * kFFP + (((kk * 4 + lg) ^ (lr & 7)) << 3)];
#pragma unroll
            for (int j = 0; j < 2; ++j) {
                const bf16x8 bv = *(const bf16x8*)&W2T_[(long)(nc * 128 + w * 32 + j * 16 + lr) * kFFP + kk * 32 + lg * 8];
                acc[j] = __builtin_amdgcn_mfma_f32_16x16x32_bf16(a, bv, acc[j], 0, 0, 0);
            }
        }
#pragma unroll
        for (int j = 0; j < 2; ++j)
#pragma unroll
            for (int rr = 0; rr < 4; ++rr) {
                const int row = r0 + lg * 4 + rr, col = nc * 128 + w * 32 + j * 16 + lr;
                X[(long)row * kC + col] += acc[j][rr] + b2_[col];
            }
    }
}

// ---------------------------------------------------------------------------
// Fused attention (proven v7): swapped QK^T, exp2 (Q pre-scaled by log2e/8),
// E packed bf16x2 in swizzled Ps, per-lane sums + cross-wave reduce, am
// bf16x2-packed, PV swizzled-LDS x direct-L2 V. 2 barriers/b.
// ---------------------------------------------------------------------------
__global__ __launch_bounds__(512, 2)
void attn_fused(const bf16* __restrict__ Qg, const bf16* __restrict__ Kg,
                const bf16* __restrict__ VTg, bf16* __restrict__ yg,
                float* __restrict__ attm)
{
    __shared__ __align__(16) bf16 Ps[32 * kT];    // 64 KB; epilogue: fp32 [32][512]
    __shared__ float reds[32][8];
    __shared__ float invs[32];
    const int tid = threadIdx.x, lane = tid & 63, w = tid >> 6;
    const int lr = lane & 15, lg = lane >> 4;
    const int bid = blockIdx.x, r_ = bid >> 3;
    const int h = ((bid & 7) << 1) | (r_ & 1);    // XCD-local head
    const int q0 = (r_ >> 1) * 32;
    const int rh = w >> 2, ch = w & 3;            // PV: wave = one 16x16 y tile

    const int tbB = w * 16 + (lg >> 1);
    const int loB = (lg & 1) * 4;
    unsigned am_[2][4][2][2];
#pragma unroll
    for (int hf = 0; hf < 2; ++hf)
#pragma unroll
        for (int j = 0; j < 4; ++j)
#pragma unroll
            for (int qt = 0; qt < 2; ++qt)
#pragma unroll
                for (int d = 0; d < 2; ++d) am_[hf][j][qt][d] = 0u;

    for (int b = 0; b < kB; ++b) {
        const long bh = (long)b * kH + h;
        const bf16* Qb = Qg + (bh * kT + q0) * kHD;
        const bf16* Kb = Kg + bh * kT * kHD;
        const bf16* Vb = VTg + bh * (long)kHD * kT;

        if (b) __syncthreads();

        bf16x8 qf[2][2];
#pragma unroll
        for (int qt = 0; qt < 2; ++qt)
#pragma unroll
            for (int kk = 0; kk < 2; ++kk)
                qf[qt][kk] = *(const bf16x8*)&Qb[(long)(qt * 16 + lr) * kHD + kk * 32 + lg * 8];

        float s[2] = {0.f, 0.f};

#pragma unroll
        for (int hf = 0; hf < 2; ++hf) {
            f32x4 acc[4][2];
#pragma unroll
            for (int j = 0; j < 4; ++j)
#pragma unroll
                for (int qt = 0; qt < 2; ++qt) acc[j][qt] = (f32x4){0.f, 0.f, 0.f, 0.f};
#pragma unroll
            for (int j = 0; j < 4; ++j) {
                const int trow = w * 128 + hf * 64 + j * 16 + lr;
#pragma unroll
                for (int kk = 0; kk < 2; ++kk) {
                    const bf16x8 kf = *(const bf16x8*)&Kb[(long)trow * kHD + kk * 32 + lg * 8];
                    acc[j][0] = __builtin_amdgcn_mfma_f32_16x16x32_bf16(kf, qf[0][kk], acc[j][0], 0, 0, 0);
                    acc[j][1] = __builtin_amdgcn_mfma_f32_16x16x32_bf16(kf, qf[1][kk], acc[j][1], 0, 0, 0);
                }
            }
#pragma unroll
            for (int j = 0; j < 4; ++j) {
                const int tb = tbB + hf * 8 + j * 2;
#pragma unroll
                for (int qt = 0; qt < 2; ++qt) {
                    float e0 = exp2f(acc[j][qt][0]);
                    float e1 = exp2f(acc[j][qt][1]);
                    float e2 = exp2f(acc[j][qt][2]);
                    float e3 = exp2f(acc[j][qt][3]);
                    s[qt] += (e0 + e1) + (e2 + e3);
                    const int q = qt * 16 + lr;
                    uint2 pk; pk.x = bpack(e0, e1); pk.y = bpack(e2, e3);
                    *(uint2*)&Ps[q * kT + ((tb ^ (q & 7)) << 3) + loB] = pk;
                }
            }
        }

#pragma unroll
        for (int qt = 0; qt < 2; ++qt) {
            s[qt] += __shfl_xor(s[qt], 16);
            s[qt] += __shfl_xor(s[qt], 32);
        }
        if (lane < 16) { reds[lane][w] = s[0]; reds[16 + lane][w] = s[1]; }
        __syncthreads();

        float inv[2], iv4[2];
#pragma unroll
        for (int qt = 0; qt < 2; ++qt) {
            const int q = qt * 16 + lr;
            float4 a = *(const float4*)&reds[q][0];
            float4 c = *(const float4*)&reds[q][4];
            float tot = ((a.x + a.y) + (a.z + a.w)) + ((c.x + c.y) + (c.z + c.w));
            inv[qt] = __builtin_amdgcn_rcpf(tot);
            iv4[qt] = inv[qt] * 0.25f;
        }
        if (lane < 16) { invs[lane] = inv[0]; invs[16 + lane] = inv[1]; }

#pragma unroll
        for (int hf = 0; hf < 2; ++hf)
#pragma unroll
            for (int j = 0; j < 4; ++j) {
                const int tb = tbB + hf * 8 + j * 2;
#pragma unroll
                for (int qt = 0; qt < 2; ++qt) {
                    const int q = qt * 16 + lr;
                    uint2 e2 = *(const uint2*)&Ps[q * kT + ((tb ^ (q & 7)) << 3) + loB];
#pragma unroll
                    for (int d = 0; d < 2; ++d) {
                        unsigned ev = d ? e2.y : e2.x;
                        unsigned av = am_[hf][j][qt][d];
                        float n0 = blo(av) + blo(ev) * iv4[qt];
                        float n1 = bhi(av) + bhi(ev) * iv4[qt];
                        am_[hf][j][qt][d] = bpack(n0, n1);
                    }
                }
            }

        f32x4 yacc = (f32x4){0.f, 0.f, 0.f, 0.f};
        const int rowA = rh * 16 + lr;
        const long dRow = (long)(ch * 16 + lr) * kT;
#pragma unroll 4
        for (int kb = 0; kb < 32; ++kb) {
            const bf16x8 a = *(const bf16x8*)&Ps[rowA * kT + (((kb * 4 + lg) ^ (rowA & 7)) << 3)];
            const bf16x8 v = *(const bf16x8*)&Vb[dRow + kb * 32 + lg * 8];
            yacc = __builtin_amdgcn_mfma_f32_16x16x32_bf16(a, v, yacc, 0, 0, 0);
        }
#pragma unroll
        for (int rr = 0; rr < 4; ++rr) {
            const float iv = invs[rh * 16 + lg * 4 + rr];
            yg[((long)b * kT + q0 + rh * 16 + lg * 4 + rr) * kC + h * kHD + ch * 16 + lr]
                = (bf16)(yacc[rr] * iv);
        }
    }

    __syncthreads();
    float* amf = (float*)Ps;
#pragma unroll
    for (int th = 0; th < 2; ++th) {
        if ((w >> 2) == th) {
#pragma unroll
            for (int hf = 0; hf < 2; ++hf)
#pragma unroll
                for (int j = 0; j < 4; ++j) {
                    const int tl = (w & 3) * 128 + hf * 64 + j * 16 + lg * 4;
#pragma unroll
                    for (int qt = 0; qt < 2; ++qt) {
                        const int q = qt * 16 + lr;
#pragma unroll
                        for (int d = 0; d < 2; ++d) {
                            unsigned av = am_[hf][j][qt][d];
                            amf[q * 512 + tl + 2 * d]     = blo(av);
                            amf[q * 512 + tl + 2 * d + 1] = bhi(av);
                        }
                    }
                }
        }
        __syncthreads();
#pragma unroll
        for (int p = 0; p < 8; ++p) {
            const int f = p * 512 + tid;
            const int row = f >> 7, c4 = f & 127;
            float4 v = *(const float4*)&amf[row * 512 + c4 * 4];
            *(float4*)&attm[((long)h * kT + q0 + row) * kT + th * 512 + c4 * 4] = v;
        }
        __syncthreads();
    }
}

__global__ __launch_bounds__(256)
void pool_kernel(const float* __restrict__ xf, float* __restrict__ pooled)
{
    const int c = blockIdx.x * 256 + threadIdx.x;
    const int b = blockIdx.y;
    const int t0 = blockIdx.z * 128;
    float s = 0.f;
    for (int t = t0; t < t0 + 128; ++t) s += xf[((long)b * kT + t) * kC + c];
    atomicAdd(&pooled[b * kC + c], s * (1.f / kT));
}

// ---------------------------------------------------------------------------
extern "C" void kernel_launch(void* const* d_in, const int* in_sizes, int n_in,
                              void* d_out, int out_size, void* d_ws, size_t ws_size,
                              hipStream_t stream)
{
    const int*   idx  = (const int*)d_in[0];
    const float* tok  = (const float*)d_in[1];
    const float* pos  = (const float*)d_in[2];
    const float* Wq   = (const float*)d_in[3];
    const float* bq   = (const float*)d_in[4];
    const float* Wk   = (const float*)d_in[5];
    const float* bk   = (const float*)d_in[6];
    const float* Wv   = (const float*)d_in[7];
    const float* bv   = (const float*)d_in[8];
    const float* Wo   = (const float*)d_in[9];
    const float* bo   = (const float*)d_in[10];
    const float* ln1w = (const float*)d_in[11];
    const float* ln1b = (const float*)d_in[12];
    const float* ln2w = (const float*)d_in[13];
    const float* ln2b = (const float*)d_in[14];
    const float* W1   = (const float*)d_in[15];
    const float* b1   = (const float*)d_in[16];
    const float* W2   = (const float*)d_in[17];
    const float* b2   = (const float*)d_in[18];
    const float* lnfw = (const float*)d_in[19];
    const float* lnfb = (const float*)d_in[20];

    char* ws = (char*)d_ws;
    long off = 0;
    auto alloc = [&](long bytes) { char* p = ws + off; off += (bytes + 255) & ~255L; return p; };
    bf16*  WQKVT = (bf16*)alloc((long)kL * 3 * kC * kC * 2);
    bf16*  WOT   = (bf16*)alloc((long)kL * kC * kC * 2);
    bf16*  W1T   = (bf16*)alloc((long)kL * kFFP * kC * 2);
    bf16*  W2T   = (bf16*)alloc((long)kL * kC * kFFP * 2);
    float* BQKV  = (float*)alloc((long)kL * 3 * kC * 4);
    float* X     = (float*)alloc((long)kM * kC * 4);
    bf16*  Hbuf  = (bf16*)alloc((long)kM * kC * 2);
    bf16*  QKV   = (bf16*)alloc(3L * kM * kC * 2);
    bf16*  Y     = (bf16*)alloc((long)kM * kC * 2);
    float* XF    = (float*)alloc((long)kM * kC * 4);

    float* pooled = (float*)d_out;
    float* attm_base = pooled + kB * kC;

    prep_kernel<<<17472, 256, 0, stream>>>(Wq, Wk, Wv, Wo, W1, W2, bq, bk, bv,
                                           WQKVT, WOT, W1T, W2T, BQKV, pooled);
    embed_kernel<<<kM, 256, 0, stream>>>(idx, tok, pos, X);

    for (int l = 0; l < kL; ++l) {
        ln_kernel<<<kM, 256, 0, stream>>>(X, ln1w + l * kC, ln1b + l * kC, Hbuf, nullptr, 0);
        gemm_bf16<2, 2, 4, 4, 0, 1><<<dim3(8, 32, 3), 256, 0, stream>>>(
            Hbuf, 0L, WQKVT + (long)l * 3 * kC * kC, (long)kC * kC,
            BQKV + l * 3 * kC, kC, QKV, (long)kM * kC, nullptr,
            kC, kC, kC, kC);
        attn_fused<<<dim3(512), 512, 0, stream>>>(
            QKV, QKV + (long)kM * kC, QKV + 2L * kM * kC, Y,
            attm_base + (long)l * kH * kT * kT);
        gemm_bf16<2, 2, 4, 4, 4, 1><<<dim3(8, 32, 1), 256, 0, stream>>>(
            Y, 0L, WOT + (long)l * kC * kC, 0L, bo + l * kC, 0,
            nullptr, 0L, X, kC, kC, kC, kC);
        ff_fused<<<256, 256, 0, stream>>>(X, ln2w + l * kC, ln2b + l * kC,
                                          W1T + (long)l * kFFP * kC, b1 + l * kFF,
                                          W2T + (long)l * kC * kFFP, b2 + l * kC);
    }
    ln_kernel<<<kM, 256, 0, stream>>>(X, lnfw, lnfb, nullptr, XF, 1);
    pool_kernel<<<dim3(4, kB, 8), 256, 0, stream>>>(XF, pooled);
}

// Round 9
// 980.211 us; speedup vs baseline: 2.4954x; 1.0112x over previous
//
#include <hip/hip_runtime.h>

typedef __bf16 bf16;
typedef __bf16 bf16x4 __attribute__((ext_vector_type(4)));
typedef __bf16 bf16x8 __attribute__((ext_vector_type(8)));
typedef float  f32x4  __attribute__((ext_vector_type(4)));

static constexpr int kC   = 1024;
static constexpr int kT   = 1024;
static constexpr int kB   = 4;
static constexpr int kH   = 16;
static constexpr int kHD  = 64;
static constexpr int kL   = 4;
static constexpr int kFF  = 100;
static constexpr int kFFP = 128;
static constexpr int kM   = kB * kT;

__device__ __forceinline__ void gload16(const bf16* g, bf16* l)
{
    __builtin_amdgcn_global_load_lds(
        (const __attribute__((address_space(1))) void*)g,
        (__attribute__((address_space(3))) void*)l, 16, 0, 0);
}

__device__ __forceinline__ unsigned bpack(float a, float b)
{
    bf16 x = (bf16)a, y = (bf16)b;
    unsigned short ux = __builtin_bit_cast(unsigned short, x);
    unsigned short uy = __builtin_bit_cast(unsigned short, y);
    return (unsigned)ux | ((unsigned)uy << 16);
}
__device__ __forceinline__ float blo(unsigned u) { return __builtin_bit_cast(float, u << 16); }
__device__ __forceinline__ float bhi(unsigned u) { return __builtin_bit_cast(float, u & 0xffff0000u); }

// ---------------------------------------------------------------------------
// One-shot prep: all weight transposes/converts + bias pack + pooled zero.
// ---------------------------------------------------------------------------
__global__ __launch_bounds__(256)
void prep_kernel(const float* __restrict__ Wq, const float* __restrict__ Wk,
                 const float* __restrict__ Wv, const float* __restrict__ Wo,
                 const float* __restrict__ W1, const float* __restrict__ W2,
                 const float* __restrict__ bq, const float* __restrict__ bk,
                 const float* __restrict__ bv,
                 bf16* __restrict__ WQKVT, bf16* __restrict__ WOT,
                 bf16* __restrict__ W1T, bf16* __restrict__ W2T,
                 float* __restrict__ BQKV, float* __restrict__ pooled)
{
    __shared__ float tile[32][33];
    const int bid = blockIdx.x, tid = threadIdx.x;
    const float* src; bf16* dst; int K, N, KP, NP, bx, by;
    if (bid < 12288) {                       // Wq/Wk/Wv -> WQKVT[l][which]
        const int slab = bid >> 10, within = bid & 1023;
        const int l = slab / 3, which = slab % 3;
        const float* W = (which == 0) ? Wq : (which == 1) ? Wk : Wv;
        src = W + (long)l * kC * kC;
        dst = WQKVT + (long)l * 3 * kC * kC + (long)which * kC * kC;
        K = N = KP = NP = kC; bx = within & 31; by = within >> 5;
    } else if (bid < 16384) {                // Wo -> WOT
        const int t = bid - 12288, z = t >> 10, within = t & 1023;
        src = Wo + (long)z * kC * kC; dst = WOT + (long)z * kC * kC;
        K = N = KP = NP = kC; bx = within & 31; by = within >> 5;
    } else if (bid < 16896) {                // W1 -> W1T (N=100 -> NP=128)
        const int t = bid - 16384, z = t >> 7, within = t & 127;
        src = W1 + (long)z * kC * kFF; dst = W1T + (long)z * kFFP * kC;
        K = kC; N = kFF; KP = kC; NP = kFFP; bx = within & 3; by = within >> 2;
    } else if (bid < 17408) {                // W2 -> W2T (K=100 -> KP=128)
        const int t = bid - 16896, z = t >> 7, within = t & 127;
        src = W2 + (long)z * kFF * kC; dst = W2T + (long)z * kC * kFFP;
        K = kFF; N = kC; KP = kFFP; NP = kC; bx = within & 31; by = within >> 5;
    } else if (bid < 17456) {                // bias pack
        const int gid = (bid - 17408) * 256 + tid;
        const int l = gid / (3 * kC), wq = (gid / kC) % 3, c = gid & (kC - 1);
        const float* s = (wq == 0) ? bq : (wq == 1) ? bk : bv;
        BQKV[gid] = s[l * kC + c];
        return;
    } else {                                 // zero pooled
        const int i = (bid - 17456) * 256 + tid;
        if (i < kB * kC) pooled[i] = 0.f;
        return;
    }
    const int n0 = bx * 32, k0 = by * 32;
    const int tx = tid & 31, ty = tid >> 5;
#pragma unroll
    for (int i = 0; i < 4; ++i) {
        int k = k0 + ty + i * 8, n = n0 + tx;
        tile[ty + i * 8][tx] = (k < K && n < N) ? src[(long)k * N + n] : 0.f;
    }
    __syncthreads();
#pragma unroll
    for (int i = 0; i < 4; ++i) {
        int n = n0 + ty + i * 8, k = k0 + tx;
        if (n < NP && k < KP) dst[(long)n * KP + k] = (bf16)tile[tx][ty + i * 8];
    }
}

__global__ __launch_bounds__(256)
void embed_kernel(const int* __restrict__ idx, const float* __restrict__ tok,
                  const float* __restrict__ pos, float* __restrict__ x)
{
    const int m = blockIdx.x;
    const int c = threadIdx.x * 4;
    const int t = m & (kT - 1);
    const long tk = (long)idx[m] * kC;
    float4 a = *(const float4*)&tok[tk + c];
    float4 b = *(const float4*)&pos[(long)t * kC + c];
    float4 o; o.x = a.x + b.x; o.y = a.y + b.y; o.z = a.z + b.z; o.w = a.w + b.w;
    *(float4*)&x[(long)m * kC + c] = o;
}

__global__ __launch_bounds__(256)
void ln_kernel(const float* __restrict__ x, const float* __restrict__ g,
               const float* __restrict__ be, bf16* __restrict__ ob)
{
    __shared__ float red[8];
    const long row = blockIdx.x;
    const int tid = threadIdx.x, lane = tid & 63, wv = tid >> 6;
    const float4 v = *(const float4*)&x[row * kC + tid * 4];
    float s = v.x + v.y + v.z + v.w;
    float s2 = v.x * v.x + v.y * v.y + v.z * v.z + v.w * v.w;
#pragma unroll
    for (int o = 32; o > 0; o >>= 1) { s += __shfl_down(s, o); s2 += __shfl_down(s2, o); }
    if (!lane) { red[wv] = s; red[4 + wv] = s2; }
    __syncthreads();
    s  = red[0] + red[1] + red[2] + red[3];
    s2 = red[4] + red[5] + red[6] + red[7];
    const float mean = s * (1.f / kC);
    const float var  = s2 * (1.f / kC) - mean * mean;
    const float rstd = rsqrtf(var + 1e-5f);
    const float4 gg = *(const float4*)&g[tid * 4];
    const float4 bb = *(const float4*)&be[tid * 4];
    bf16x4 o;
    o[0] = (bf16)((v.x - mean) * rstd * gg.x + bb.x);
    o[1] = (bf16)((v.y - mean) * rstd * gg.y + bb.y);
    o[2] = (bf16)((v.z - mean) * rstd * gg.z + bb.z);
    o[3] = (bf16)((v.w - mean) * rstd * gg.w + bb.w);
    *(bf16x4*)&ob[row * kC + tid * 4] = o;
}

// ---------------------------------------------------------------------------
// MFMA GEMM (proven): C = A * B^T.  GL=1: global_load_lds, 128x128 tile.
// MODE 0: QKV (z=0 q*0.125*log2e -> [B,H,T,HD]; z=1 k; z=2 v -> VT)
// MODE 4: resid += acc + bias
// ---------------------------------------------------------------------------
template<int WAVES_M, int WAVES_N, int AI, int BJ, int MODE, int GL>
__global__ __launch_bounds__(256)
void gemm_bf16(const bf16* __restrict__ Ag, long strideA,
               const bf16* __restrict__ Bg, long strideB,
               const float* __restrict__ bias, int strideBias,
               bf16* __restrict__ outb, long strideOut,
               float* __restrict__ resid,
               int N, int K, int lda, int ldb)
{
    constexpr int BM = WAVES_M * AI * 16;
    constexpr int BN = WAVES_N * BJ * 16;
    constexpr int BK = 64;
    constexpr int LK = GL ? BK : (BK + 8);
    __shared__ __align__(16) bf16 As[BM * LK];
    __shared__ __align__(16) bf16 Bs[BN * LK];
    const int tid = threadIdx.x, lane = tid & 63, wv = tid >> 6;
    const int wm = wv / WAVES_N, wn = wv % WAVES_N;
    const int lr = lane & 15, lg = lane >> 4;
    const int z = blockIdx.z;
    const bf16* A = Ag + (long)z * strideA;
    const bf16* B = Bg + (long)z * strideB;
    const float* bi = bias ? bias + (long)z * strideBias : nullptr;
    const int m0 = blockIdx.y * BM, n0 = blockIdx.x * BN;

    f32x4 acc[AI][BJ];
#pragma unroll
    for (int i = 0; i < AI; ++i)
#pragma unroll
        for (int j = 0; j < BJ; ++j) acc[i][j] = (f32x4){0.f, 0.f, 0.f, 0.f};

    for (int k0 = 0; k0 < K; k0 += BK) {
        if constexpr (GL) {
            static_assert(BM == 128 && BN == 128, "GL path needs 128x128 tile");
            const int srow = wv * 32 + (lane >> 3);
            const int gcb  = (lane & 7) ^ (lane >> 3);
#pragma unroll
            for (int p = 0; p < 4; ++p) {
                gload16(A + (long)(m0 + srow + p * 8) * lda + k0 + gcb * 8,
                        &As[(wv * 32 + p * 8) * BK]);
                gload16(B + (long)(n0 + srow + p * 8) * ldb + k0 + gcb * 8,
                        &Bs[(wv * 32 + p * 8) * BK]);
            }
        } else {
            constexpr int AP = (BM * BK) / (256 * 8);
#pragma unroll
            for (int p = 0; p < AP; ++p) {
                int r = p * 32 + (tid >> 3), c = (tid & 7) * 8;
                *(uint4*)&As[r * LK + c] = *(const uint4*)&A[(long)(m0 + r) * lda + k0 + c];
            }
            constexpr int BP = (BN * BK) / (256 * 8);
#pragma unroll
            for (int p = 0; p < BP; ++p) {
                int r = p * 32 + (tid >> 3), c = (tid & 7) * 8;
                *(uint4*)&Bs[r * LK + c] = *(const uint4*)&B[(long)(n0 + r) * ldb + k0 + c];
            }
        }
        __syncthreads();
#pragma unroll
        for (int kk = 0; kk < 2; ++kk) {
            bf16x8 af[AI], bfv[BJ];
#pragma unroll
            for (int i = 0; i < AI; ++i) {
                const int r = wm * AI * 16 + i * 16 + lr;
                const int c = GL ? (((kk * 4 + lg) ^ (lr & 7)) * 8) : (kk * 32 + lg * 8);
                af[i] = *(const bf16x8*)&As[r * LK + c];
            }
#pragma unroll
            for (int j = 0; j < BJ; ++j) {
                const int r = wn * BJ * 16 + j * 16 + lr;
                const int c = GL ? (((kk * 4 + lg) ^ (lr & 7)) * 8) : (kk * 32 + lg * 8);
                bfv[j] = *(const bf16x8*)&Bs[r * LK + c];
            }
#pragma unroll
            for (int i = 0; i < AI; ++i)
#pragma unroll
                for (int j = 0; j < BJ; ++j)
                    acc[i][j] = __builtin_amdgcn_mfma_f32_16x16x32_bf16(af[i], bfv[j], acc[i][j], 0, 0, 0);
        }
        __syncthreads();
    }

#pragma unroll
    for (int i = 0; i < AI; ++i)
#pragma unroll
        for (int j = 0; j < BJ; ++j)
#pragma unroll
            for (int rr = 0; rr < 4; ++rr) {
                const int grow = m0 + wm * AI * 16 + i * 16 + lg * 4 + rr;
                const int gcol = n0 + wn * BJ * 16 + j * 16 + lr;
                float v = acc[i][j][rr];
                if constexpr (MODE == 0) {
                    v += bi[gcol];
                    if (z == 0) v *= 0.125f * 1.44269504f;  // scale * log2(e)
                    const int b = grow >> 10, t = grow & (kT - 1);
                    const int hh = gcol >> 6, hd = gcol & 63;
                    long o = (long)z * strideOut;
                    if (z == 2) o += (((long)b * kH + hh) * kHD + hd) * kT + t;  // VT
                    else        o += (((long)b * kH + hh) * kT + t) * kHD + hd;  // Q/K
                    outb[o] = (bf16)v;
                } else {
                    v += bi[gcol];
                    resid[(long)grow * N + gcol] += v;
                }
            }
}

// ---------------------------------------------------------------------------
// Fused FF: ln2 + FF1(relu) + FF2(+=X), one block per 16 rows, 4 waves.
// ---------------------------------------------------------------------------
__global__ __launch_bounds__(256, 2)
void ff_fused(float* __restrict__ X, const float* __restrict__ g,
              const float* __restrict__ be,
              const bf16* __restrict__ W1T_, const float* __restrict__ b1_,
              const bf16* __restrict__ W2T_, const float* __restrict__ b2_)
{
    __shared__ __align__(16) bf16 Hs[16 * kC];
    __shared__ __align__(16) bf16 F1s[16 * kFFP];
    const int tid = threadIdx.x, lane = tid & 63, w = tid >> 6;
    const int lr = lane & 15, lg = lane >> 4;
    const int r0 = blockIdx.x * 16;

    // Phase A: ln2 on rows r0..r0+15 -> Hs (16B-block XOR swizzle by row&7)
    {
        const int row = tid >> 4, c16 = tid & 15;
        float4 xv[16];
        float s1 = 0.f, s2 = 0.f;
#pragma unroll
        for (int p = 0; p < 8; ++p) {
            const float* base = &X[(long)(r0 + row) * kC + p * 128 + c16 * 8];
            xv[2 * p]     = *(const float4*)base;
            xv[2 * p + 1] = *(const float4*)(base + 4);
#pragma unroll
            for (int e = 0; e < 4; ++e) {
                float a0 = ((const float*)&xv[2 * p])[e], a1 = ((const float*)&xv[2 * p + 1])[e];
                s1 += a0 + a1; s2 += a0 * a0 + a1 * a1;
            }
        }
#pragma unroll
        for (int off = 1; off < 16; off <<= 1) { s1 += __shfl_xor(s1, off); s2 += __shfl_xor(s2, off); }
        const float mean = s1 * (1.f / kC);
        const float rstd = rsqrtf(s2 * (1.f / kC) - mean * mean + 1e-5f);
#pragma unroll
        for (int p = 0; p < 8; ++p) {
            const int c0 = p * 128 + c16 * 8;
            float4 g0 = *(const float4*)&g[c0],  g1 = *(const float4*)&g[c0 + 4];
            float4 b0 = *(const float4*)&be[c0], b1v = *(const float4*)&be[c0 + 4];
            float h[8];
#pragma unroll
            for (int e = 0; e < 4; ++e) {
                h[e]     = (((const float*)&xv[2 * p])[e]     - mean) * rstd * ((const float*)&g0)[e] + ((const float*)&b0)[e];
                h[4 + e] = (((const float*)&xv[2 * p + 1])[e] - mean) * rstd * ((const float*)&g1)[e] + ((const float*)&b1v)[e];
            }
            uint4 hv;
            hv.x = bpack(h[0], h[1]); hv.y = bpack(h[2], h[3]);
            hv.z = bpack(h[4], h[5]); hv.w = bpack(h[6], h[7]);
            const int cb = c16 + p * 16;
            *(uint4*)&Hs[row * kC + ((cb ^ (row & 7)) << 3)] = hv;
        }
    }
    __syncthreads();

    // Phase B: FF1 f1[16][128] = relu(Hs @ W1T + b1) -> F1s (swizzled)
    // two independent accumulator chains per j (split by kk parity)
    {
        f32x4 accA[2], accB[2];
#pragma unroll
        for (int j = 0; j < 2; ++j) { accA[j] = (f32x4){0,0,0,0}; accB[j] = (f32x4){0,0,0,0}; }
        for (int k0 = 0; k0 < kC; k0 += 64) {
            const bf16x8 a0 = *(const bf16x8*)&Hs[lr * kC + ((((k0 >> 3) + 0 * 4 + lg) ^ (lr & 7)) << 3)];
            const bf16x8 a1 = *(const bf16x8*)&Hs[lr * kC + ((((k0 >> 3) + 1 * 4 + lg) ^ (lr & 7)) << 3)];
#pragma unroll
            for (int j = 0; j < 2; ++j) {
                const bf16x8 b0 = *(const bf16x8*)&W1T_[(long)(w * 32 + j * 16 + lr) * kC + k0 + 0 * 32 + lg * 8];
                const bf16x8 b1 = *(const bf16x8*)&W1T_[(long)(w * 32 + j * 16 + lr) * kC + k0 + 1 * 32 + lg * 8];
                accA[j] = __builtin_amdgcn_mfma_f32_16x16x32_bf16(a0, b0, accA[j], 0, 0, 0);
                accB[j] = __builtin_amdgcn_mfma_f32_16x16x32_bf16(a1, b1, accB[j], 0, 0, 0);
            }
        }
#pragma unroll
        for (int j = 0; j < 2; ++j)
#pragma unroll
            for (int rr = 0; rr < 4; ++rr) {
                const int row = lg * 4 + rr, col = w * 32 + j * 16 + lr;
                float v = accA[j][rr] + accB[j][rr] + (col < kFF ? b1_[col] : 0.f);
                F1s[row * kFFP + (((col >> 3) ^ (row & 7)) << 3) + (col & 7)] = (bf16)fmaxf(v, 0.f);
            }
    }
    __syncthreads();

    // Phase C: FF2  X[16][1024] += F1s @ W2T + b2   (8 n-chunks of 128)
    for (int nc = 0; nc < 8; ++nc) {
        f32x4 acc[2];
        acc[0] = (f32x4){0.f, 0.f, 0.f, 0.f};
        acc[1] = (f32x4){0.f, 0.f, 0.f, 0.f};
#pragma unroll
        for (int kk = 0; kk < 4; ++kk) {
            const bf16x8 a = *(const bf16x8*)&F1s[lr * kFFP + (((kk * 4 + lg) ^ (lr & 7)) << 3)];
#pragma unroll
            for (int j = 0; j < 2; ++j) {
                const bf16x8 bv = *(const bf16x8*)&W2T_[(long)(nc * 128 + w * 32 + j * 16 + lr) * kFFP + kk * 32 + lg * 8];
                acc[j] = __builtin_amdgcn_mfma_f32_16x16x32_bf16(a, bv, acc[j], 0, 0, 0);
            }
        }
#pragma unroll
        for (int j = 0; j < 2; ++j)
#pragma unroll
            for (int rr = 0; rr < 4; ++rr) {
                const int row = r0 + lg * 4 + rr, col = nc * 128 + w * 32 + j * 16 + lr;
                X[(long)row * kC + col] += acc[j][rr] + b2_[col];
            }
    }
}

// ---------------------------------------------------------------------------
// Fused attention (v8): v7 + setprio around MFMA clusters, dual-chain PV,
// 32-bit offsets in hot loads.
// ---------------------------------------------------------------------------
__global__ __launch_bounds__(512, 2)
void attn_fused(const bf16* __restrict__ Qg, const bf16* __restrict__ Kg,
                const bf16* __restrict__ VTg, bf16* __restrict__ yg,
                float* __restrict__ attm)
{
    __shared__ __align__(16) bf16 Ps[32 * kT];    // 64 KB; epilogue: fp32 [32][512]
    __shared__ float reds[32][8];
    __shared__ float invs[32];
    const int tid = threadIdx.x, lane = tid & 63, w = tid >> 6;
    const int lr = lane & 15, lg = lane >> 4;
    const int bid = blockIdx.x, r_ = bid >> 3;
    const int h = ((bid & 7) << 1) | (r_ & 1);    // XCD-local head
    const int q0 = (r_ >> 1) * 32;
    const int rh = w >> 2, ch = w & 3;            // PV: wave = one 16x16 y tile

    const int tbB = w * 16 + (lg >> 1);
    const int loB = (lg & 1) * 4;
    unsigned am_[2][4][2][2];
#pragma unroll
    for (int hf = 0; hf < 2; ++hf)
#pragma unroll
        for (int j = 0; j < 4; ++j)
#pragma unroll
            for (int qt = 0; qt < 2; ++qt)
#pragma unroll
                for (int d = 0; d < 2; ++d) am_[hf][j][qt][d] = 0u;

    for (int b = 0; b < kB; ++b) {
        const long bh = (long)b * kH + h;
        const bf16* Qb = Qg + (bh * kT + q0) * kHD;
        const bf16* Kb = Kg + bh * kT * kHD;
        const bf16* Vb = VTg + bh * (long)kHD * kT;

        if (b) __syncthreads();

        bf16x8 qf[2][2];
#pragma unroll
        for (int qt = 0; qt < 2; ++qt)
#pragma unroll
            for (int kk = 0; kk < 2; ++kk)
                qf[qt][kk] = *(const bf16x8*)&Qb[(qt * 16 + lr) * kHD + kk * 32 + lg * 8];

        float s[2] = {0.f, 0.f};

#pragma unroll
        for (int hf = 0; hf < 2; ++hf) {
            f32x4 acc[4][2];
#pragma unroll
            for (int j = 0; j < 4; ++j)
#pragma unroll
                for (int qt = 0; qt < 2; ++qt) acc[j][qt] = (f32x4){0.f, 0.f, 0.f, 0.f};
            __builtin_amdgcn_s_setprio(1);
#pragma unroll
            for (int j = 0; j < 4; ++j) {
                const int trow = w * 128 + hf * 64 + j * 16 + lr;
#pragma unroll
                for (int kk = 0; kk < 2; ++kk) {
                    const bf16x8 kf = *(const bf16x8*)&Kb[trow * kHD + kk * 32 + lg * 8];
                    acc[j][0] = __builtin_amdgcn_mfma_f32_16x16x32_bf16(kf, qf[0][kk], acc[j][0], 0, 0, 0);
                    acc[j][1] = __builtin_amdgcn_mfma_f32_16x16x32_bf16(kf, qf[1][kk], acc[j][1], 0, 0, 0);
                }
            }
            __builtin_amdgcn_s_setprio(0);
#pragma unroll
            for (int j = 0; j < 4; ++j) {
                const int tb = tbB + hf * 8 + j * 2;
#pragma unroll
                for (int qt = 0; qt < 2; ++qt) {
                    float e0 = exp2f(acc[j][qt][0]);
                    float e1 = exp2f(acc[j][qt][1]);
                    float e2 = exp2f(acc[j][qt][2]);
                    float e3 = exp2f(acc[j][qt][3]);
                    s[qt] += (e0 + e1) + (e2 + e3);
                    const int q = qt * 16 + lr;
                    uint2 pk; pk.x = bpack(e0, e1); pk.y = bpack(e2, e3);
                    *(uint2*)&Ps[q * kT + ((tb ^ (q & 7)) << 3) + loB] = pk;
                }
            }
        }

#pragma unroll
        for (int qt = 0; qt < 2; ++qt) {
            s[qt] += __shfl_xor(s[qt], 16);
            s[qt] += __shfl_xor(s[qt], 32);
        }
        if (lane < 16) { reds[lane][w] = s[0]; reds[16 + lane][w] = s[1]; }
        __syncthreads();

        float inv[2], iv4[2];
#pragma unroll
        for (int qt = 0; qt < 2; ++qt) {
            const int q = qt * 16 + lr;
            float4 a = *(const float4*)&reds[q][0];
            float4 c = *(const float4*)&reds[q][4];
            float tot = ((a.x + a.y) + (a.z + a.w)) + ((c.x + c.y) + (c.z + c.w));
            inv[qt] = __builtin_amdgcn_rcpf(tot);
            iv4[qt] = inv[qt] * 0.25f;
        }
        if (lane < 16) { invs[lane] = inv[0]; invs[16 + lane] = inv[1]; }

#pragma unroll
        for (int hf = 0; hf < 2; ++hf)
#pragma unroll
            for (int j = 0; j < 4; ++j) {
                const int tb = tbB + hf * 8 + j * 2;
#pragma unroll
                for (int qt = 0; qt < 2; ++qt) {
                    const int q = qt * 16 + lr;
                    uint2 e2 = *(const uint2*)&Ps[q * kT + ((tb ^ (q & 7)) << 3) + loB];
#pragma unroll
                    for (int d = 0; d < 2; ++d) {
                        unsigned ev = d ? e2.y : e2.x;
                        unsigned av = am_[hf][j][qt][d];
                        float n0 = blo(av) + blo(ev) * iv4[qt];
                        float n1 = bhi(av) + bhi(ev) * iv4[qt];
                        am_[hf][j][qt][d] = bpack(n0, n1);
                    }
                }
            }

        // PV: dual independent accumulator chains, setprio around MFMA
        f32x4 yacc0 = (f32x4){0.f, 0.f, 0.f, 0.f};
        f32x4 yacc1 = (f32x4){0.f, 0.f, 0.f, 0.f};
        const int rowA = rh * 16 + lr;
        const int dRow = (ch * 16 + lr) * kT;
        __builtin_amdgcn_s_setprio(1);
#pragma unroll 4
        for (int kb = 0; kb < 32; kb += 2) {
            const bf16x8 a0 = *(const bf16x8*)&Ps[rowA * kT + (((kb * 4 + lg) ^ (rowA & 7)) << 3)];
            const bf16x8 v0 = *(const bf16x8*)&Vb[dRow + kb * 32 + lg * 8];
            const bf16x8 a1 = *(const bf16x8*)&Ps[rowA * kT + ((((kb + 1) * 4 + lg) ^ (rowA & 7)) << 3)];
            const bf16x8 v1 = *(const bf16x8*)&Vb[dRow + (kb + 1) * 32 + lg * 8];
            yacc0 = __builtin_amdgcn_mfma_f32_16x16x32_bf16(a0, v0, yacc0, 0, 0, 0);
            yacc1 = __builtin_amdgcn_mfma_f32_16x16x32_bf16(a1, v1, yacc1, 0, 0, 0);
        }
        __builtin_amdgcn_s_setprio(0);
#pragma unroll
        for (int rr = 0; rr < 4; ++rr) {
            const float iv = invs[rh * 16 + lg * 4 + rr];
            yg[((long)b * kT + q0 + rh * 16 + lg * 4 + rr) * kC + h * kHD + ch * 16 + lr]
                = (bf16)((yacc0[rr] + yacc1[rr]) * iv);
        }
    }

    __syncthreads();
    float* amf = (float*)Ps;
#pragma unroll
    for (int th = 0; th < 2; ++th) {
        if ((w >> 2) == th) {
#pragma unroll
            for (int hf = 0; hf < 2; ++hf)
#pragma unroll
                for (int j = 0; j < 4; ++j) {
                    const int tl = (w & 3) * 128 + hf * 64 + j * 16 + lg * 4;
#pragma unroll
                    for (int qt = 0; qt < 2; ++qt) {
                        const int q = qt * 16 + lr;
#pragma unroll
                        for (int d = 0; d < 2; ++d) {
                            unsigned av = am_[hf][j][qt][d];
                            amf[q * 512 + tl + 2 * d]     = blo(av);
                            amf[q * 512 + tl + 2 * d + 1] = bhi(av);
                        }
                    }
                }
        }
        __syncthreads();
#pragma unroll
        for (int p = 0; p < 8; ++p) {
            const int f = p * 512 + tid;
            const int row = f >> 7, c4 = f & 127;
            float4 v = *(const float4*)&amf[row * 512 + c4 * 4];
            *(float4*)&attm[((long)h * kT + q0 + row) * kT + th * 512 + c4 * 4] = v;
        }
        __syncthreads();
    }
}

// pooled[b][c] = mean_t hb[b,t,c]  (bf16 input)
__global__ __launch_bounds__(256)
void pool_kernel(const bf16* __restrict__ hb, float* __restrict__ pooled)
{
    const int c = blockIdx.x * 256 + threadIdx.x;
    const int b = blockIdx.y;
    const int t0 = blockIdx.z * 128;
    float s = 0.f;
    for (int t = t0; t < t0 + 128; ++t) s += (float)hb[((long)b * kT + t) * kC + c];
    atomicAdd(&pooled[b * kC + c], s * (1.f / kT));
}

// ---------------------------------------------------------------------------
extern "C" void kernel_launch(void* const* d_in, const int* in_sizes, int n_in,
                              void* d_out, int out_size, void* d_ws, size_t ws_size,
                              hipStream_t stream)
{
    const int*   idx  = (const int*)d_in[0];
    const float* tok  = (const float*)d_in[1];
    const float* pos  = (const float*)d_in[2];
    const float* Wq   = (const float*)d_in[3];
    const float* bq   = (const float*)d_in[4];
    const float* Wk   = (const float*)d_in[5];
    const float* bk   = (const float*)d_in[6];
    const float* Wv   = (const float*)d_in[7];
    const float* bv   = (const float*)d_in[8];
    const float* Wo   = (const float*)d_in[9];
    const float* bo   = (const float*)d_in[10];
    const float* ln1w = (const float*)d_in[11];
    const float* ln1b = (const float*)d_in[12];
    const float* ln2w = (const float*)d_in[13];
    const float* ln2b = (const float*)d_in[14];
    const float* W1   = (const float*)d_in[15];
    const float* b1   = (const float*)d_in[16];
    const float* W2   = (const float*)d_in[17];
    const float* b2   = (const float*)d_in[18];
    const float* lnfw = (const float*)d_in[19];
    const float* lnfb = (const float*)d_in[20];

    char* ws = (char*)d_ws;
    long off = 0;
    auto alloc = [&](long bytes) { char* p = ws + off; off += (bytes + 255) & ~255L; return p; };
    bf16*  WQKVT = (bf16*)alloc((long)kL * 3 * kC * kC * 2);
    bf16*  WOT   = (bf16*)alloc((long)kL * kC * kC * 2);
    bf16*  W1T   = (bf16*)alloc((long)kL * kFFP * kC * 2);
    bf16*  W2T   = (bf16*)alloc((long)kL * kC * kFFP * 2);
    float* BQKV  = (float*)alloc((long)kL * 3 * kC * 4);
    float* X     = (float*)alloc((long)kM * kC * 4);
    bf16*  Hbuf  = (bf16*)alloc((long)kM * kC * 2);
    bf16*  QKV   = (bf16*)alloc(3L * kM * kC * 2);
    bf16*  Y     = (bf16*)alloc((long)kM * kC * 2);

    float* pooled = (float*)d_out;
    float* attm_base = pooled + kB * kC;

    prep_kernel<<<17472, 256, 0, stream>>>(Wq, Wk, Wv, Wo, W1, W2, bq, bk, bv,
                                           WQKVT, WOT, W1T, W2T, BQKV, pooled);
    embed_kernel<<<kM, 256, 0, stream>>>(idx, tok, pos, X);

    for (int l = 0; l < kL; ++l) {
        ln_kernel<<<kM, 256, 0, stream>>>(X, ln1w + l * kC, ln1b + l * kC, Hbuf);
        gemm_bf16<2, 2, 4, 4, 0, 1><<<dim3(8, 32, 3), 256, 0, stream>>>(
            Hbuf, 0L, WQKVT + (long)l * 3 * kC * kC, (long)kC * kC,
            BQKV + l * 3 * kC, kC, QKV, (long)kM * kC, nullptr,
            kC, kC, kC, kC);
        attn_fused<<<dim3(512), 512, 0, stream>>>(
            QKV, QKV + (long)kM * kC, QKV + 2L * kM * kC, Y,
            attm_base + (long)l * kH * kT * kT);
        gemm_bf16<2, 2, 4, 4, 4, 1><<<dim3(8, 32, 1), 256, 0, stream>>>(
            Y, 0L, WOT + (long)l * kC * kC, 0L, bo + l * kC, 0,
            nullptr, 0L, X, kC, kC, kC, kC);
        ff_fused<<<256, 256, 0, stream>>>(X, ln2w + l * kC, ln2b + l * kC,
                                          W1T + (long)l * kFFP * kC, b1 + l * kFF,
                                          W2T + (long)l * kC * kFFP, b2 + l * kC);
    }
    ln_kernel<<<kM, 256, 0, stream>>>(X, lnfw, lnfb, Hbuf);
    pool_kernel<<<dim3(4, kB, 8), 256, 0, stream>>>(Hbuf, pooled);
}